// Round 10
// baseline (475.066 us; speedup 1.0000x reference)
//
#include <hip/hip_runtime.h>
#include <hip/hip_bf16.h>

// S4D regressor, chunked-scan MFMA formulation.
// R10: R9's zero-barrier independent-wave structure + residency fix:
// __launch_bounds__(256,6) caps VGPR at 84 -> 6 waves/SIMD (was 104 -> 4),
// and xf fragments are re-loaded in phase 3 instead of carried across the
// scan (cuts long-range liveness so the cap is reachable without spills).
// B=32, L=4096, C=128, N=64, DEPTH=4, OUT=1.

#define BB     32
#define LL     4096
#define CC     128
#define NN     64
#define DEPTH_ 4
#define EPSV   1e-5f

typedef __attribute__((ext_vector_type(8))) short short8;
typedef __attribute__((ext_vector_type(4))) short short4v;
typedef __attribute__((ext_vector_type(4))) float f32x4;
typedef __hip_bfloat16 bf16;

#define MFMA(a, b, c) __builtin_amdgcn_mfma_f32_16x16x32_bf16(a, b, c, 0, 0, 0)

__device__ __forceinline__ bf16 tobf(float x) { return __float2bfloat16(x); }
__device__ __forceinline__ short bfbits(float x) {
    union { bf16 b; short s; } u; u.b = __float2bfloat16(x); return u.s;
}

// ---------------------------------------------------------------------------
// P0: per (d,c,n): lam=exp(dt*A), dta=dt*A, cb2=2*C*(lam-1)/A, lamT=lam^64
// ---------------------------------------------------------------------------
__global__ __launch_bounds__(64) void p0_kernel(
    const float* __restrict__ log_dt, const float* __restrict__ A_real,
    const float* __restrict__ A_imag, const float* __restrict__ C_re,
    const float* __restrict__ C_im, float2* __restrict__ lam,
    float2* __restrict__ dta, float2* __restrict__ cb2,
    float2* __restrict__ lamT)
{
    int d = blockIdx.y, c = blockIdx.x, n = threadIdx.x;
    int idx = (d * CC + c) * NN + n;
    float dt  = expf(log_dt[d * CC + c]);
    float Ar  = -expf(A_real[idx]);
    float Ai  = A_imag[idx];
    float dtr = dt * Ar, dti = dt * Ai;
    float e   = expf(dtr);
    float lr  = e * cosf(dti), li = e * sinf(dti);
    float m    = Ar * Ar + Ai * Ai;
    float inv  = 1.0f / m;
    float numr = lr - 1.0f, numi = li;
    float br   = (numr * Ar + numi * Ai) * inv;
    float bi   = (numi * Ar - numr * Ai) * inv;
    float cre  = C_re[idx], cim = C_im[idx];
    lam[idx]  = make_float2(lr, li);
    dta[idx]  = make_float2(dtr, dti);
    cb2[idx]  = make_float2(2.0f * (cre * br - cim * bi),
                            2.0f * (cre * bi + cim * br));
    float eT = expf(64.0f * dtr);
    lamT[idx] = make_float2(eT * cosf(64.0f * dti), eT * sinf(64.0f * dti));
}

// ---------------------------------------------------------------------------
// P1: Kloc[d][c][delta] = Re sum_n cb2_n lam_n^delta   (delta = 0..63)
// ---------------------------------------------------------------------------
__global__ __launch_bounds__(64) void p1_kernel(
    const float2* __restrict__ cb2, const float2* __restrict__ lam,
    float* __restrict__ Kloc)
{
    __shared__ float st[64 * 65];
    int d = blockIdx.y, c = blockIdx.x, n = threadIdx.x;
    float2 p = cb2[(d * CC + c) * NN + n];
    float2 l = lam[(d * CC + c) * NN + n];
    for (int t = 0; t < 64; ++t) {
        st[t * 65 + n] = p.x;
        float nr = p.x * l.x - p.y * l.y;
        p.y = p.x * l.y + p.y * l.x;
        p.x = nr;
    }
    __syncthreads();
    float s = 0.0f;
#pragma unroll 16
    for (int j = 0; j < 64; ++j) s += st[n * 65 + j];
    Kloc[(d * CC + c) * 64 + n] = s;
}

// ---------------------------------------------------------------------------
// P2V: Vp packed [d][c][nf=8][ks=2][lane=64][e=8]: B[k][q]=Re/Im(lam_n^{63-k})
// ---------------------------------------------------------------------------
__global__ __launch_bounds__(256) void p2v_kernel(
    const float2* __restrict__ dta, bf16* __restrict__ Vp)
{
    int t = blockIdx.x * 256 + threadIdx.x;
    int e = t & 7, l = (t >> 3) & 63, ks = (t >> 9) & 1;
    int nf = (t >> 10) & 7, c = (t >> 13) & 127, d = t >> 20;
    int q = nf * 16 + (l & 15);
    int k = ks * 32 + (l >> 4) * 8 + e;
    int n = q >> 1;
    float2 a = dta[(d * CC + c) * NN + n];
    float p  = (float)(63 - k);
    float mag = expf(p * a.x);
    float ang = p * a.y;
    float val = (q & 1) ? mag * sinf(ang) : mag * cosf(ang);
    Vp[t] = tobf(val);
}

// ---------------------------------------------------------------------------
// P2W: W2p packed [d][c][nf=4][ks=6][lane=64][e=8]
// ---------------------------------------------------------------------------
__global__ __launch_bounds__(256) void p2w_kernel(
    const float2* __restrict__ dta, const float2* __restrict__ cb2,
    const float* __restrict__ Kloc, const float* __restrict__ Dskip,
    bf16* __restrict__ W2p)
{
    int t = blockIdx.x * 256 + threadIdx.x;
    int e = t & 7, l = (t >> 3) & 63;
    int r = t >> 9;
    int ks = r % 6; r /= 6;
    int nf = r & 3; r >>= 2;
    int c  = r & 127;
    int d  = r >> 7;
    int i = nf * 16 + (l & 15);
    int k = ks * 32 + (l >> 4) * 8 + e;
    float val;
    if (k < 64) {
        val = (k <= i) ? Kloc[(d * CC + c) * 64 + (i - k)] : 0.0f;
        if (k == i) val += Dskip[d * CC + c] + 1.0f;
    } else {
        int q = k - 64, n = q >> 1;
        float2 a  = dta[(d * CC + c) * NN + n];
        float2 cb = cb2[(d * CC + c) * NN + n];
        float p   = (float)(i + 1);
        float mag = expf(p * a.x);
        float ang = p * a.y;
        float re = mag * cosf(ang), im = mag * sinf(ang);
        float wre = cb.x * re - cb.y * im;
        float wim = cb.x * im + cb.y * re;
        val = (q & 1) ? -wim : wre;
    }
    W2p[t] = tobf(val);
}

// ---------------------------------------------------------------------------
// x [B,L,C] fp32 -> xt [B][C][L] bf16
// ---------------------------------------------------------------------------
__global__ __launch_bounds__(256) void transpose_kernel(
    const float* __restrict__ x, bf16* __restrict__ xt)
{
    __shared__ float t[64][65];
    int ct = blockIdx.x, lt = blockIdx.y, b = blockIdx.z;
    int tx = threadIdx.x & 63, ty = threadIdx.x >> 6;
    const size_t xbase = ((size_t)b * LL + (size_t)lt * 64) * CC + (size_t)ct * 64;
#pragma unroll
    for (int i = 0; i < 16; ++i)
        t[ty + 4 * i][tx] = x[xbase + (size_t)(ty + 4 * i) * CC + tx];
    __syncthreads();
    const size_t obase = ((size_t)b * CC + (size_t)ct * 64) * LL + (size_t)lt * 64;
#pragma unroll
    for (int i = 0; i < 16; ++i)
        xt[obase + (size_t)(ty + 4 * i) * LL + tx] = tobf(t[tx][ty + 4 * i]);
}

// ---------------------------------------------------------------------------
// KS: 4 independent waves per block; wave w owns (b,c) = blockIdx*4+w.
// Zero barriers; per-wave LDS slice; VGPR capped at 84 (6 waves/SIMD).
// xf fragments re-loaded in phase 3 (not carried across the scan).
// ---------------------------------------------------------------------------
__global__ __launch_bounds__(256, 6) void ks_kernel(
    const bf16* __restrict__ u, bf16* __restrict__ v,
    const bf16* __restrict__ Vp, const bf16* __restrict__ W2p,
    const float2* __restrict__ lamT)
{
    int w  = threadIdx.x >> 6;
    int l  = threadIdx.x & 63;             // lane: MFMA lane AND mode index n
    int bc = blockIdx.x * 4 + w;           // b*C + c
    int c  = bc & (CC - 1);
    const bf16* xrow = u + (size_t)bc * LL;
    bf16*       vrow = v + (size_t)bc * LL;
    const bf16* Vpc  = Vp  + (size_t)c * 8192;
    const bf16* W2c  = W2p + (size_t)c * 12288;

    __shared__ short Sp[4][16 * 136];      // per-wave 4.35 KB slice
    short* S = Sp[w];

    const int mloc = l & 15;               // chunk-within-group (MFMA B-col)
    const int koff = (l >> 4) * 8;
    float2 lt = lamT[c * NN + l];
    float sr = 0.f, si = 0.f;              // running state, f32 entire L

#pragma unroll 1
    for (int g = 0; g < 4; ++g) {
        const bf16* xg = xrow + (g * 16 + mloc) * 64;

        // ---- phase 1 (two 4-nf halves to cap acc pressure) ----
        {
            short8 xf0 = *(const short8*)(xg + koff);
            short8 xf1 = *(const short8*)(xg + 32 + koff);
#pragma unroll
            for (int h = 0; h < 2; ++h) {
                f32x4 acc[4];
#pragma unroll
                for (int j = 0; j < 4; ++j) acc[j] = (f32x4){0.f, 0.f, 0.f, 0.f};
#pragma unroll
                for (int j = 0; j < 4; ++j) {
                    int nf = h * 4 + j;
                    short8 vf0 = *(const short8*)(Vpc + ((nf * 2 + 0) * 64 + l) * 8);
                    short8 vf1 = *(const short8*)(Vpc + ((nf * 2 + 1) * 64 + l) * 8);
                    acc[j] = MFMA(vf0, xf0, acc[j]);
                    acc[j] = MFMA(vf1, xf1, acc[j]);
                }
#pragma unroll
                for (int j = 0; j < 4; ++j) {
                    int nf = h * 4 + j;
                    short4v t;
                    t[0] = bfbits(acc[j][0]); t[1] = bfbits(acc[j][1]);
                    t[2] = bfbits(acc[j][2]); t[3] = bfbits(acc[j][3]);
                    *(short4v*)(&S[mloc * 136 + nf * 16 + (l >> 4) * 4]) = t;
                }
            }
        }
        asm volatile("" ::: "memory");     // same-wave DS pipe is in-order

        // ---- scan: 16 private steps; Sprev replaces P in place ----
#pragma unroll
        for (int k = 0; k < 16; ++k) {
            uint pk = *(const uint*)(&S[k * 136 + 2 * l]);
            union { short2 s2; uint uu; } o;
            o.s2.x = bfbits(sr); o.s2.y = bfbits(si);
            *(uint*)(&S[k * 136 + 2 * l]) = o.uu;      // Sprev for chunk k
            float pr = __uint_as_float(pk << 16);
            float pi = __uint_as_float(pk & 0xffff0000u);
            float nr = fmaf(lt.x, sr, fmaf(-lt.y, si, pr));
            si = fmaf(lt.x, si, fmaf(lt.y, sr, pi));
            sr = nr;
        }
        asm volatile("" ::: "memory");

        // ---- phase 3: K=192 GEMM over [x | Sprev]; xf re-loaded (L2 warm) --
        f32x4 o[4];
#pragma unroll
        for (int nf = 0; nf < 4; ++nf) o[nf] = (f32x4){0.f, 0.f, 0.f, 0.f};
#pragma unroll
        for (int ks = 0; ks < 6; ++ks) {
            short8 xf;
            if (ks < 2)
                xf = *(const short8*)(xg + ks * 32 + koff);
            else
                xf = *(const short8*)(&S[mloc * 136 + (ks - 2) * 32 + koff]);
#pragma unroll
            for (int nf = 0; nf < 4; ++nf) {
                short8 wf = *(const short8*)(W2c + ((nf * 6 + ks) * 64 + l) * 8);
                o[nf] = MFMA(wf, xf, o[nf]);
            }
        }
#pragma unroll
        for (int nf = 0; nf < 4; ++nf) {
            short4v t;
            t[0] = bfbits(o[nf][0]); t[1] = bfbits(o[nf][1]);
            t[2] = bfbits(o[nf][2]); t[3] = bfbits(o[nf][3]);
            *(short4v*)(vrow + (g * 16 + mloc) * 64 + nf * 16 + (l >> 4) * 4) = t;
        }
    }
}

// ---------------------------------------------------------------------------
// LayerNorm over C (bf16 in/out); final layer fuses head projection (fp32).
// ---------------------------------------------------------------------------
__global__ __launch_bounds__(256) void ln_kernel(
    const bf16* __restrict__ v, bf16* __restrict__ outx,
    const float* __restrict__ w, const float* __restrict__ bta,
    const float* __restrict__ headw, const float* __restrict__ headb,
    float* __restrict__ fout, int isfinal)
{
    __shared__ float tile[CC][65];
    __shared__ float r1[4][64];
    __shared__ float r2[4][64];
    __shared__ float mrs[2][64];
    int b    = blockIdx.y;
    int l0   = blockIdx.x * 64;
    int lane = threadIdx.x & 63;
    int cg   = threadIdx.x >> 6;
    float sum = 0.0f, sq = 0.0f;
#pragma unroll
    for (int ci = 0; ci < 32; ++ci) {
        int c = cg * 32 + ci;
        float val = __bfloat162float(v[((size_t)b * CC + c) * LL + l0 + lane]);
        tile[c][lane] = val;
        sum += val;
        sq = fmaf(val, val, sq);
    }
    r1[cg][lane] = sum;
    r2[cg][lane] = sq;
    __syncthreads();
    if (cg == 0) {
        float s = r1[0][lane] + r1[1][lane] + r1[2][lane] + r1[3][lane];
        float q = r2[0][lane] + r2[1][lane] + r2[2][lane] + r2[3][lane];
        float mean = s * (1.0f / CC);
        float var  = q * (1.0f / CC) - mean * mean;
        mrs[0][lane] = mean;
        mrs[1][lane] = rsqrtf(var + EPSV);
    }
    __syncthreads();
    float mean = mrs[0][lane], rstd = mrs[1][lane];
    if (!isfinal) {
#pragma unroll
        for (int ci = 0; ci < 32; ++ci) {
            int c = cg * 32 + ci;
            float o = (tile[c][lane] - mean) * rstd * w[c] + bta[c];
            outx[((size_t)b * CC + c) * LL + l0 + lane] = tobf(o);
        }
    } else {
        float h = 0.0f;
#pragma unroll
        for (int ci = 0; ci < 32; ++ci) {
            int c = cg * 32 + ci;
            float o = (tile[c][lane] - mean) * rstd * w[c] + bta[c];
            h = fmaf(o, headw[c], h);
        }
        __syncthreads();
        r1[cg][lane] = h;
        __syncthreads();
        if (cg == 0)
            fout[(size_t)b * LL + l0 + lane] =
                r1[0][lane] + r1[1][lane] + r1[2][lane] + r1[3][lane] + headb[0];
    }
}

// ---------------------------------------------------------------------------
extern "C" void kernel_launch(void* const* d_in, const int* in_sizes, int n_in,
                              void* d_out, int out_size, void* d_ws, size_t ws_size,
                              hipStream_t stream)
{
    const float* x      = (const float*)d_in[0];
    const float* log_dt = (const float*)d_in[1];
    const float* A_real = (const float*)d_in[2];
    const float* A_imag = (const float*)d_in[3];
    const float* C_re   = (const float*)d_in[4];
    const float* C_im   = (const float*)d_in[5];
    const float* Dskip  = (const float*)d_in[6];
    const float* norm_w = (const float*)d_in[7];
    const float* norm_b = (const float*)d_in[8];
    const float* head_w = (const float*)d_in[9];
    const float* head_b = (const float*)d_in[10];
    float* out = (float*)d_out;

    const size_t DCN = (size_t)DEPTH_ * CC * NN;
    const size_t BCL = (size_t)BB * CC * LL;

    float2* lam  = (float2*)d_ws;
    float2* dta  = lam + DCN;
    float2* cb2  = dta + DCN;
    float2* lamT = cb2 + DCN;
    float*  Kloc = (float*)(lamT + DCN);
    bf16*   u    = (bf16*)(Kloc + (size_t)DEPTH_ * CC * 64);
    bf16*   v    = u + BCL;
    bf16*   Vp   = v + BCL;
    bf16*   W2p  = Vp + (size_t)DEPTH_ * CC * 8192;

    p0_kernel<<<dim3(CC, DEPTH_), 64, 0, stream>>>(
        log_dt, A_real, A_imag, C_re, C_im, lam, dta, cb2, lamT);
    p1_kernel<<<dim3(CC, DEPTH_), 64, 0, stream>>>(cb2, lam, Kloc);
    p2v_kernel<<<(DEPTH_ * CC * 8192) / 256, 256, 0, stream>>>(dta, Vp);
    p2w_kernel<<<(DEPTH_ * CC * 12288) / 256, 256, 0, stream>>>(
        dta, cb2, Kloc, Dskip, W2p);
    transpose_kernel<<<dim3(CC / 64, LL / 64, BB), 256, 0, stream>>>(x, u);

    for (int d = 0; d < DEPTH_; ++d) {
        ks_kernel<<<(BB * CC) / 4, 256, 0, stream>>>(
            u, v, Vp + (size_t)d * CC * 8192, W2p + (size_t)d * CC * 12288,
            lamT + (size_t)d * CC * NN);
        ln_kernel<<<dim3(LL / 64, BB), 256, 0, stream>>>(
            v, u, norm_w + d * CC, norm_b + d * CC,
            head_w, head_b, out, (d == DEPTH_ - 1) ? 1 : 0);
    }
}

// Round 11
// 185.932 us; speedup vs baseline: 2.5550x; 2.5550x over previous
//
#include <hip/hip_runtime.h>
#include <hip/hip_bf16.h>

// S4D regressor, chunked-scan MFMA formulation.
// R11: kill the L2 weight wall. Block = (c, 8 b's), 512 threads: the 40 KB
// channel weight set (Vp+W2p) is staged to LDS ONCE (one barrier), then 8
// independent waves (one per b) run the zero-barrier group loop reading
// weights from LDS. Weight L2 traffic: 655 MB -> 20 MB per dispatch.
// NO __launch_bounds__ min-waves hint (R4/R8/R10 spill trap).
// B=32, L=4096, C=128, N=64, DEPTH=4, OUT=1.

#define BB     32
#define LL     4096
#define CC     128
#define NN     64
#define DEPTH_ 4
#define EPSV   1e-5f

typedef __attribute__((ext_vector_type(8))) short short8;
typedef __attribute__((ext_vector_type(4))) short short4v;
typedef __attribute__((ext_vector_type(4))) float f32x4;
typedef __hip_bfloat16 bf16;

#define MFMA(a, b, c) __builtin_amdgcn_mfma_f32_16x16x32_bf16(a, b, c, 0, 0, 0)

__device__ __forceinline__ bf16 tobf(float x) { return __float2bfloat16(x); }
__device__ __forceinline__ short bfbits(float x) {
    union { bf16 b; short s; } u; u.b = __float2bfloat16(x); return u.s;
}

// ---------------------------------------------------------------------------
// P0: per (d,c,n): lam=exp(dt*A), dta=dt*A, cb2=2*C*(lam-1)/A, lamT=lam^64
// ---------------------------------------------------------------------------
__global__ __launch_bounds__(64) void p0_kernel(
    const float* __restrict__ log_dt, const float* __restrict__ A_real,
    const float* __restrict__ A_imag, const float* __restrict__ C_re,
    const float* __restrict__ C_im, float2* __restrict__ lam,
    float2* __restrict__ dta, float2* __restrict__ cb2,
    float2* __restrict__ lamT)
{
    int d = blockIdx.y, c = blockIdx.x, n = threadIdx.x;
    int idx = (d * CC + c) * NN + n;
    float dt  = expf(log_dt[d * CC + c]);
    float Ar  = -expf(A_real[idx]);
    float Ai  = A_imag[idx];
    float dtr = dt * Ar, dti = dt * Ai;
    float e   = expf(dtr);
    float lr  = e * cosf(dti), li = e * sinf(dti);
    float m    = Ar * Ar + Ai * Ai;
    float inv  = 1.0f / m;
    float numr = lr - 1.0f, numi = li;
    float br   = (numr * Ar + numi * Ai) * inv;
    float bi   = (numi * Ar - numr * Ai) * inv;
    float cre  = C_re[idx], cim = C_im[idx];
    lam[idx]  = make_float2(lr, li);
    dta[idx]  = make_float2(dtr, dti);
    cb2[idx]  = make_float2(2.0f * (cre * br - cim * bi),
                            2.0f * (cre * bi + cim * br));
    float eT = expf(64.0f * dtr);
    lamT[idx] = make_float2(eT * cosf(64.0f * dti), eT * sinf(64.0f * dti));
}

// ---------------------------------------------------------------------------
// P1: Kloc[d][c][delta] = Re sum_n cb2_n lam_n^delta   (delta = 0..63)
// ---------------------------------------------------------------------------
__global__ __launch_bounds__(64) void p1_kernel(
    const float2* __restrict__ cb2, const float2* __restrict__ lam,
    float* __restrict__ Kloc)
{
    __shared__ float st[64 * 65];
    int d = blockIdx.y, c = blockIdx.x, n = threadIdx.x;
    float2 p = cb2[(d * CC + c) * NN + n];
    float2 l = lam[(d * CC + c) * NN + n];
    for (int t = 0; t < 64; ++t) {
        st[t * 65 + n] = p.x;
        float nr = p.x * l.x - p.y * l.y;
        p.y = p.x * l.y + p.y * l.x;
        p.x = nr;
    }
    __syncthreads();
    float s = 0.0f;
#pragma unroll 16
    for (int j = 0; j < 64; ++j) s += st[n * 65 + j];
    Kloc[(d * CC + c) * 64 + n] = s;
}

// ---------------------------------------------------------------------------
// P2V: Vp packed [d][c][nf=8][ks=2][lane=64][e=8]: B[k][q]=Re/Im(lam_n^{63-k})
// ---------------------------------------------------------------------------
__global__ __launch_bounds__(256) void p2v_kernel(
    const float2* __restrict__ dta, bf16* __restrict__ Vp)
{
    int t = blockIdx.x * 256 + threadIdx.x;
    int e = t & 7, l = (t >> 3) & 63, ks = (t >> 9) & 1;
    int nf = (t >> 10) & 7, c = (t >> 13) & 127, d = t >> 20;
    int q = nf * 16 + (l & 15);
    int k = ks * 32 + (l >> 4) * 8 + e;
    int n = q >> 1;
    float2 a = dta[(d * CC + c) * NN + n];
    float p  = (float)(63 - k);
    float mag = expf(p * a.x);
    float ang = p * a.y;
    float val = (q & 1) ? mag * sinf(ang) : mag * cosf(ang);
    Vp[t] = tobf(val);
}

// ---------------------------------------------------------------------------
// P2W: W2p packed [d][c][nf=4][ks=6][lane=64][e=8]
// ---------------------------------------------------------------------------
__global__ __launch_bounds__(256) void p2w_kernel(
    const float2* __restrict__ dta, const float2* __restrict__ cb2,
    const float* __restrict__ Kloc, const float* __restrict__ Dskip,
    bf16* __restrict__ W2p)
{
    int t = blockIdx.x * 256 + threadIdx.x;
    int e = t & 7, l = (t >> 3) & 63;
    int r = t >> 9;
    int ks = r % 6; r /= 6;
    int nf = r & 3; r >>= 2;
    int c  = r & 127;
    int d  = r >> 7;
    int i = nf * 16 + (l & 15);
    int k = ks * 32 + (l >> 4) * 8 + e;
    float val;
    if (k < 64) {
        val = (k <= i) ? Kloc[(d * CC + c) * 64 + (i - k)] : 0.0f;
        if (k == i) val += Dskip[d * CC + c] + 1.0f;
    } else {
        int q = k - 64, n = q >> 1;
        float2 a  = dta[(d * CC + c) * NN + n];
        float2 cb = cb2[(d * CC + c) * NN + n];
        float p   = (float)(i + 1);
        float mag = expf(p * a.x);
        float ang = p * a.y;
        float re = mag * cosf(ang), im = mag * sinf(ang);
        float wre = cb.x * re - cb.y * im;
        float wim = cb.x * im + cb.y * re;
        val = (q & 1) ? -wim : wre;
    }
    W2p[t] = tobf(val);
}

// ---------------------------------------------------------------------------
// x [B,L,C] fp32 -> xt [B][C][L] bf16
// ---------------------------------------------------------------------------
__global__ __launch_bounds__(256) void transpose_kernel(
    const float* __restrict__ x, bf16* __restrict__ xt)
{
    __shared__ float t[64][65];
    int ct = blockIdx.x, lt = blockIdx.y, b = blockIdx.z;
    int tx = threadIdx.x & 63, ty = threadIdx.x >> 6;
    const size_t xbase = ((size_t)b * LL + (size_t)lt * 64) * CC + (size_t)ct * 64;
#pragma unroll
    for (int i = 0; i < 16; ++i)
        t[ty + 4 * i][tx] = x[xbase + (size_t)(ty + 4 * i) * CC + tx];
    __syncthreads();
    const size_t obase = ((size_t)b * CC + (size_t)ct * 64) * LL + (size_t)lt * 64;
#pragma unroll
    for (int i = 0; i < 16; ++i)
        xt[obase + (size_t)(ty + 4 * i) * LL + tx] = tobf(t[tx][ty + 4 * i]);
}

// ---------------------------------------------------------------------------
// KS: block = (c, 8 b's), 512 threads. Stage Vp+W2p (40 KB) into LDS once
// (single barrier), then 8 independent waves run the zero-barrier group loop
// with all weight reads served from LDS (ds_read_b128, conflict-free).
// ---------------------------------------------------------------------------
__global__ __launch_bounds__(512) void ks_kernel(
    const bf16* __restrict__ u, bf16* __restrict__ v,
    const bf16* __restrict__ Vp, const bf16* __restrict__ W2p,
    const float2* __restrict__ lamT)
{
    const int c  = blockIdx.x;             // channel owned by this block
    const int w  = threadIdx.x >> 6;       // wave 0..7 -> b = bg*8+w
    const int l  = threadIdx.x & 63;       // lane: MFMA lane AND mode index n
    const int b  = blockIdx.y * 8 + w;
    const int bc = b * CC + c;
    const bf16* xrow = u + (size_t)bc * LL;
    bf16*       vrow = v + (size_t)bc * LL;

    __shared__ short Wl[8192 + 12288];     // Vp(16KB) + W2p(24KB) = 40 KB
    __shared__ short Sp[8][16 * 136];      // per-wave 4.35 KB scan slice

    // ---- stage weights: 2560 x uint4 across 512 threads, one barrier ----
    {
        uint4*       dst  = (uint4*)Wl;
        const uint4* srcV = (const uint4*)(Vp  + (size_t)c * 8192);
        const uint4* srcW = (const uint4*)(W2p + (size_t)c * 12288);
        int tid = threadIdx.x;
#pragma unroll
        for (int i = 0; i < 2; ++i)
            dst[tid + 512 * i] = srcV[tid + 512 * i];
#pragma unroll
        for (int i = 0; i < 3; ++i)
            dst[1024 + tid + 512 * i] = srcW[tid + 512 * i];
    }
    __syncthreads();                       // the ONLY barrier

    short* S = Sp[w];
    const short* W2l = Wl + 8192;
    const int mloc = l & 15;               // chunk-within-group (MFMA B-col)
    const int koff = (l >> 4) * 8;
    float2 lt = lamT[c * NN + l];
    float sr = 0.f, si = 0.f;              // running state, f32 entire L

#pragma unroll 1
    for (int g = 0; g < 4; ++g) {
        const bf16* xg = xrow + (g * 16 + mloc) * 64;

        // ---- phase 1 (two 4-nf halves to cap acc pressure) ----
        {
            short8 xf0 = *(const short8*)(xg + koff);
            short8 xf1 = *(const short8*)(xg + 32 + koff);
#pragma unroll
            for (int h = 0; h < 2; ++h) {
                f32x4 acc[4];
#pragma unroll
                for (int j = 0; j < 4; ++j) acc[j] = (f32x4){0.f, 0.f, 0.f, 0.f};
#pragma unroll
                for (int j = 0; j < 4; ++j) {
                    int nf = h * 4 + j;
                    short8 vf0 = *(const short8*)(&Wl[((nf * 2 + 0) * 64 + l) * 8]);
                    short8 vf1 = *(const short8*)(&Wl[((nf * 2 + 1) * 64 + l) * 8]);
                    acc[j] = MFMA(vf0, xf0, acc[j]);
                    acc[j] = MFMA(vf1, xf1, acc[j]);
                }
#pragma unroll
                for (int j = 0; j < 4; ++j) {
                    int nf = h * 4 + j;
                    short4v t;
                    t[0] = bfbits(acc[j][0]); t[1] = bfbits(acc[j][1]);
                    t[2] = bfbits(acc[j][2]); t[3] = bfbits(acc[j][3]);
                    *(short4v*)(&S[mloc * 136 + nf * 16 + (l >> 4) * 4]) = t;
                }
            }
        }
        asm volatile("" ::: "memory");     // same-wave DS pipe is in-order

        // ---- scan: 16 private steps; Sprev replaces P in place ----
#pragma unroll
        for (int k = 0; k < 16; ++k) {
            uint pk = *(const uint*)(&S[k * 136 + 2 * l]);
            union { short2 s2; uint uu; } o;
            o.s2.x = bfbits(sr); o.s2.y = bfbits(si);
            *(uint*)(&S[k * 136 + 2 * l]) = o.uu;      // Sprev for chunk k
            float pr = __uint_as_float(pk << 16);
            float pi = __uint_as_float(pk & 0xffff0000u);
            float nr = fmaf(lt.x, sr, fmaf(-lt.y, si, pr));
            si = fmaf(lt.x, si, fmaf(lt.y, sr, pi));
            sr = nr;
        }
        asm volatile("" ::: "memory");

        // ---- phase 3: K=192 GEMM over [x | Sprev]; weights from LDS ----
        f32x4 o[4];
#pragma unroll
        for (int nf = 0; nf < 4; ++nf) o[nf] = (f32x4){0.f, 0.f, 0.f, 0.f};
#pragma unroll
        for (int ks = 0; ks < 6; ++ks) {
            short8 xf;
            if (ks < 2)
                xf = *(const short8*)(xg + ks * 32 + koff);
            else
                xf = *(const short8*)(&S[mloc * 136 + (ks - 2) * 32 + koff]);
#pragma unroll
            for (int nf = 0; nf < 4; ++nf) {
                short8 wf = *(const short8*)(&W2l[((nf * 6 + ks) * 64 + l) * 8]);
                o[nf] = MFMA(wf, xf, o[nf]);
            }
        }
#pragma unroll
        for (int nf = 0; nf < 4; ++nf) {
            short4v t;
            t[0] = bfbits(o[nf][0]); t[1] = bfbits(o[nf][1]);
            t[2] = bfbits(o[nf][2]); t[3] = bfbits(o[nf][3]);
            *(short4v*)(vrow + (g * 16 + mloc) * 64 + nf * 16 + (l >> 4) * 4) = t;
        }
    }
}

// ---------------------------------------------------------------------------
// LayerNorm over C (bf16 in/out); final layer fuses head projection (fp32).
// ---------------------------------------------------------------------------
__global__ __launch_bounds__(256) void ln_kernel(
    const bf16* __restrict__ v, bf16* __restrict__ outx,
    const float* __restrict__ w, const float* __restrict__ bta,
    const float* __restrict__ headw, const float* __restrict__ headb,
    float* __restrict__ fout, int isfinal)
{
    __shared__ float tile[CC][65];
    __shared__ float r1[4][64];
    __shared__ float r2[4][64];
    __shared__ float mrs[2][64];
    int b    = blockIdx.y;
    int l0   = blockIdx.x * 64;
    int lane = threadIdx.x & 63;
    int cg   = threadIdx.x >> 6;
    float sum = 0.0f, sq = 0.0f;
#pragma unroll
    for (int ci = 0; ci < 32; ++ci) {
        int c = cg * 32 + ci;
        float val = __bfloat162float(v[((size_t)b * CC + c) * LL + l0 + lane]);
        tile[c][lane] = val;
        sum += val;
        sq = fmaf(val, val, sq);
    }
    r1[cg][lane] = sum;
    r2[cg][lane] = sq;
    __syncthreads();
    if (cg == 0) {
        float s = r1[0][lane] + r1[1][lane] + r1[2][lane] + r1[3][lane];
        float q = r2[0][lane] + r2[1][lane] + r2[2][lane] + r2[3][lane];
        float mean = s * (1.0f / CC);
        float var  = q * (1.0f / CC) - mean * mean;
        mrs[0][lane] = mean;
        mrs[1][lane] = rsqrtf(var + EPSV);
    }
    __syncthreads();
    float mean = mrs[0][lane], rstd = mrs[1][lane];
    if (!isfinal) {
#pragma unroll
        for (int ci = 0; ci < 32; ++ci) {
            int c = cg * 32 + ci;
            float o = (tile[c][lane] - mean) * rstd * w[c] + bta[c];
            outx[((size_t)b * CC + c) * LL + l0 + lane] = tobf(o);
        }
    } else {
        float h = 0.0f;
#pragma unroll
        for (int ci = 0; ci < 32; ++ci) {
            int c = cg * 32 + ci;
            float o = (tile[c][lane] - mean) * rstd * w[c] + bta[c];
            h = fmaf(o, headw[c], h);
        }
        __syncthreads();
        r1[cg][lane] = h;
        __syncthreads();
        if (cg == 0)
            fout[(size_t)b * LL + l0 + lane] =
                r1[0][lane] + r1[1][lane] + r1[2][lane] + r1[3][lane] + headb[0];
    }
}

// ---------------------------------------------------------------------------
extern "C" void kernel_launch(void* const* d_in, const int* in_sizes, int n_in,
                              void* d_out, int out_size, void* d_ws, size_t ws_size,
                              hipStream_t stream)
{
    const float* x      = (const float*)d_in[0];
    const float* log_dt = (const float*)d_in[1];
    const float* A_real = (const float*)d_in[2];
    const float* A_imag = (const float*)d_in[3];
    const float* C_re   = (const float*)d_in[4];
    const float* C_im   = (const float*)d_in[5];
    const float* Dskip  = (const float*)d_in[6];
    const float* norm_w = (const float*)d_in[7];
    const float* norm_b = (const float*)d_in[8];
    const float* head_w = (const float*)d_in[9];
    const float* head_b = (const float*)d_in[10];
    float* out = (float*)d_out;

    const size_t DCN = (size_t)DEPTH_ * CC * NN;
    const size_t BCL = (size_t)BB * CC * LL;

    float2* lam  = (float2*)d_ws;
    float2* dta  = lam + DCN;
    float2* cb2  = dta + DCN;
    float2* lamT = cb2 + DCN;
    float*  Kloc = (float*)(lamT + DCN);
    bf16*   u    = (bf16*)(Kloc + (size_t)DEPTH_ * CC * 64);
    bf16*   v    = u + BCL;
    bf16*   Vp   = v + BCL;
    bf16*   W2p  = Vp + (size_t)DEPTH_ * CC * 8192;

    p0_kernel<<<dim3(CC, DEPTH_), 64, 0, stream>>>(
        log_dt, A_real, A_imag, C_re, C_im, lam, dta, cb2, lamT);
    p1_kernel<<<dim3(CC, DEPTH_), 64, 0, stream>>>(cb2, lam, Kloc);
    p2v_kernel<<<(DEPTH_ * CC * 8192) / 256, 256, 0, stream>>>(dta, Vp);
    p2w_kernel<<<(DEPTH_ * CC * 12288) / 256, 256, 0, stream>>>(
        dta, cb2, Kloc, Dskip, W2p);
    transpose_kernel<<<dim3(CC / 64, LL / 64, BB), 256, 0, stream>>>(x, u);

    for (int d = 0; d < DEPTH_; ++d) {
        ks_kernel<<<dim3(CC, BB / 8), 512, 0, stream>>>(
            u, v, Vp + (size_t)d * CC * 8192, W2p + (size_t)d * CC * 12288,
            lamT + (size_t)d * CC * NN);
        ln_kernel<<<dim3(LL / 64, BB), 256, 0, stream>>>(
            v, u, norm_w + d * CC, norm_b + d * CC,
            head_w, head_b, out, (d == DEPTH_ - 1) ? 1 : 0);
    }
}

// Round 12
// 184.544 us; speedup vs baseline: 2.5743x; 1.0075x over previous
//
#include <hip/hip_runtime.h>
#include <hip/hip_bf16.h>

// S4D regressor, chunked-scan MFMA formulation.
// R12: LN fused into the next layer's ks. Middle LayerNorms become a tiny
// stats kernel (per-(b,l) mean/rstd, 1 MB, L2-hot); ks normalizes x-fragments
// on load with per-block scalar w[c],beta[c]. Saves 67 MB HBM per middle
// layer (536 -> 402 MB chain traffic). R11's LDS weight staging kept.
// NO __launch_bounds__ min-waves hints (R4/R8/R10 spill trap).
// B=32, L=4096, C=128, N=64, DEPTH=4, OUT=1.

#define BB     32
#define LL     4096
#define CC     128
#define NN     64
#define DEPTH_ 4
#define EPSV   1e-5f

typedef __attribute__((ext_vector_type(8))) short short8;
typedef __attribute__((ext_vector_type(4))) short short4v;
typedef __attribute__((ext_vector_type(4))) float f32x4;
typedef __hip_bfloat16 bf16;

#define MFMA(a, b, c) __builtin_amdgcn_mfma_f32_16x16x32_bf16(a, b, c, 0, 0, 0)

__device__ __forceinline__ bf16 tobf(float x) { return __float2bfloat16(x); }
__device__ __forceinline__ short bfbits(float x) {
    union { bf16 b; short s; } u; u.b = __float2bfloat16(x); return u.s;
}
__device__ __forceinline__ float frombits(short s) {
    return __uint_as_float(((uint)(ushort)s) << 16);
}

// ---------------------------------------------------------------------------
// P0: per (d,c,n): lam=exp(dt*A), dta=dt*A, cb2=2*C*(lam-1)/A, lamT=lam^64
// ---------------------------------------------------------------------------
__global__ __launch_bounds__(64) void p0_kernel(
    const float* __restrict__ log_dt, const float* __restrict__ A_real,
    const float* __restrict__ A_imag, const float* __restrict__ C_re,
    const float* __restrict__ C_im, float2* __restrict__ lam,
    float2* __restrict__ dta, float2* __restrict__ cb2,
    float2* __restrict__ lamT)
{
    int d = blockIdx.y, c = blockIdx.x, n = threadIdx.x;
    int idx = (d * CC + c) * NN + n;
    float dt  = expf(log_dt[d * CC + c]);
    float Ar  = -expf(A_real[idx]);
    float Ai  = A_imag[idx];
    float dtr = dt * Ar, dti = dt * Ai;
    float e   = expf(dtr);
    float lr  = e * cosf(dti), li = e * sinf(dti);
    float m    = Ar * Ar + Ai * Ai;
    float inv  = 1.0f / m;
    float numr = lr - 1.0f, numi = li;
    float br   = (numr * Ar + numi * Ai) * inv;
    float bi   = (numi * Ar - numr * Ai) * inv;
    float cre  = C_re[idx], cim = C_im[idx];
    lam[idx]  = make_float2(lr, li);
    dta[idx]  = make_float2(dtr, dti);
    cb2[idx]  = make_float2(2.0f * (cre * br - cim * bi),
                            2.0f * (cre * bi + cim * br));
    float eT = expf(64.0f * dtr);
    lamT[idx] = make_float2(eT * cosf(64.0f * dti), eT * sinf(64.0f * dti));
}

// ---------------------------------------------------------------------------
// P1: Kloc[d][c][delta] = Re sum_n cb2_n lam_n^delta   (delta = 0..63)
// ---------------------------------------------------------------------------
__global__ __launch_bounds__(64) void p1_kernel(
    const float2* __restrict__ cb2, const float2* __restrict__ lam,
    float* __restrict__ Kloc)
{
    __shared__ float st[64 * 65];
    int d = blockIdx.y, c = blockIdx.x, n = threadIdx.x;
    float2 p = cb2[(d * CC + c) * NN + n];
    float2 l = lam[(d * CC + c) * NN + n];
    for (int t = 0; t < 64; ++t) {
        st[t * 65 + n] = p.x;
        float nr = p.x * l.x - p.y * l.y;
        p.y = p.x * l.y + p.y * l.x;
        p.x = nr;
    }
    __syncthreads();
    float s = 0.0f;
#pragma unroll 16
    for (int j = 0; j < 64; ++j) s += st[n * 65 + j];
    Kloc[(d * CC + c) * 64 + n] = s;
}

// ---------------------------------------------------------------------------
// P2V: Vp packed [d][c][nf=8][ks=2][lane=64][e=8]: B[k][q]=Re/Im(lam_n^{63-k})
// ---------------------------------------------------------------------------
__global__ __launch_bounds__(256) void p2v_kernel(
    const float2* __restrict__ dta, bf16* __restrict__ Vp)
{
    int t = blockIdx.x * 256 + threadIdx.x;
    int e = t & 7, l = (t >> 3) & 63, ks = (t >> 9) & 1;
    int nf = (t >> 10) & 7, c = (t >> 13) & 127, d = t >> 20;
    int q = nf * 16 + (l & 15);
    int k = ks * 32 + (l >> 4) * 8 + e;
    int n = q >> 1;
    float2 a = dta[(d * CC + c) * NN + n];
    float p  = (float)(63 - k);
    float mag = expf(p * a.x);
    float ang = p * a.y;
    float val = (q & 1) ? mag * sinf(ang) : mag * cosf(ang);
    Vp[t] = tobf(val);
}

// ---------------------------------------------------------------------------
// P2W: W2p packed [d][c][nf=4][ks=6][lane=64][e=8]
// ---------------------------------------------------------------------------
__global__ __launch_bounds__(256) void p2w_kernel(
    const float2* __restrict__ dta, const float2* __restrict__ cb2,
    const float* __restrict__ Kloc, const float* __restrict__ Dskip,
    bf16* __restrict__ W2p)
{
    int t = blockIdx.x * 256 + threadIdx.x;
    int e = t & 7, l = (t >> 3) & 63;
    int r = t >> 9;
    int ks = r % 6; r /= 6;
    int nf = r & 3; r >>= 2;
    int c  = r & 127;
    int d  = r >> 7;
    int i = nf * 16 + (l & 15);
    int k = ks * 32 + (l >> 4) * 8 + e;
    float val;
    if (k < 64) {
        val = (k <= i) ? Kloc[(d * CC + c) * 64 + (i - k)] : 0.0f;
        if (k == i) val += Dskip[d * CC + c] + 1.0f;
    } else {
        int q = k - 64, n = q >> 1;
        float2 a  = dta[(d * CC + c) * NN + n];
        float2 cb = cb2[(d * CC + c) * NN + n];
        float p   = (float)(i + 1);
        float mag = expf(p * a.x);
        float ang = p * a.y;
        float re = mag * cosf(ang), im = mag * sinf(ang);
        float wre = cb.x * re - cb.y * im;
        float wim = cb.x * im + cb.y * re;
        val = (q & 1) ? -wim : wre;
    }
    W2p[t] = tobf(val);
}

// ---------------------------------------------------------------------------
// x [B,L,C] fp32 -> xt [B][C][L] bf16
// ---------------------------------------------------------------------------
__global__ __launch_bounds__(256) void transpose_kernel(
    const float* __restrict__ x, bf16* __restrict__ xt)
{
    __shared__ float t[64][65];
    int ct = blockIdx.x, lt = blockIdx.y, b = blockIdx.z;
    int tx = threadIdx.x & 63, ty = threadIdx.x >> 6;
    const size_t xbase = ((size_t)b * LL + (size_t)lt * 64) * CC + (size_t)ct * 64;
#pragma unroll
    for (int i = 0; i < 16; ++i)
        t[ty + 4 * i][tx] = x[xbase + (size_t)(ty + 4 * i) * CC + tx];
    __syncthreads();
    const size_t obase = ((size_t)b * CC + (size_t)ct * 64) * LL + (size_t)lt * 64;
#pragma unroll
    for (int i = 0; i < 16; ++i)
        xt[obase + (size_t)(ty + 4 * i) * LL + tx] = tobf(t[tx][ty + 4 * i]);
}

// ---------------------------------------------------------------------------
// STATS: per-(b,l) LayerNorm statistics (mean, rstd) from v [B][C][L] bf16.
// Block covers (b, 256 l's); vectorized short4 (8B) loads; ~6 us.
// ---------------------------------------------------------------------------
__global__ __launch_bounds__(256) void stats_kernel(
    const bf16* __restrict__ v, float2* __restrict__ st)
{
    __shared__ float rs[4][256];
    __shared__ float rq[4][256];
    int b  = blockIdx.y;
    int l0 = blockIdx.x * 256;
    int lt = threadIdx.x & 63;
    int cg = threadIdx.x >> 6;
    const short* vv = (const short*)v;
    float s[4] = {0.f, 0.f, 0.f, 0.f};
    float q[4] = {0.f, 0.f, 0.f, 0.f};
#pragma unroll
    for (int ci = 0; ci < 32; ++ci) {
        int c = cg * 32 + ci;
        short4v r = *(const short4v*)(&vv[((size_t)b * CC + c) * LL + l0 + lt * 4]);
#pragma unroll
        for (int j = 0; j < 4; ++j) {
            float f = frombits(r[j]);
            s[j] += f;
            q[j] = fmaf(f, f, q[j]);
        }
    }
#pragma unroll
    for (int j = 0; j < 4; ++j) {
        rs[cg][lt * 4 + j] = s[j];
        rq[cg][lt * 4 + j] = q[j];
    }
    __syncthreads();
    if (cg == 0) {
#pragma unroll
        for (int j = 0; j < 4; ++j) {
            int li = lt * 4 + j;
            float ts = rs[0][li] + rs[1][li] + rs[2][li] + rs[3][li];
            float tq = rq[0][li] + rq[1][li] + rq[2][li] + rq[3][li];
            float mean = ts * (1.0f / CC);
            float var  = tq * (1.0f / CC) - mean * mean;
            st[(size_t)b * LL + l0 + li] = make_float2(mean, rsqrtf(var + EPSV));
        }
    }
}

// ---------------------------------------------------------------------------
// KS: block = (c, 8 b's), 512 threads. Weights (40 KB) staged in LDS once.
// If st != nullptr, x-fragments are LayerNorm-normalized on load:
//   xn = f*a + (beta - mu*a),  a = rstd * w[c]   (w[c],beta[c] block-scalar).
// ---------------------------------------------------------------------------
__global__ __launch_bounds__(512) void ks_kernel(
    const bf16* __restrict__ u, bf16* __restrict__ v,
    const bf16* __restrict__ Vp, const bf16* __restrict__ W2p,
    const float2* __restrict__ lamT, const float2* __restrict__ st,
    const float* __restrict__ nw, const float* __restrict__ nb)
{
    const int c  = blockIdx.x;             // channel owned by this block
    const int w  = threadIdx.x >> 6;       // wave 0..7 -> b = bg*8+w
    const int l  = threadIdx.x & 63;       // lane: MFMA lane AND mode index n
    const int b  = blockIdx.y * 8 + w;
    const int bc = b * CC + c;
    const bf16* xrow = u + (size_t)bc * LL;
    bf16*       vrow = v + (size_t)bc * LL;

    __shared__ short Wl[8192 + 12288];     // Vp(16KB) + W2p(24KB) = 40 KB
    __shared__ short Sp[8][16 * 136];      // per-wave 4.35 KB scan slice

    // ---- stage weights: 2560 x uint4 across 512 threads, one barrier ----
    {
        uint4*       dst  = (uint4*)Wl;
        const uint4* srcV = (const uint4*)(Vp  + (size_t)c * 8192);
        const uint4* srcW = (const uint4*)(W2p + (size_t)c * 12288);
        int tid = threadIdx.x;
#pragma unroll
        for (int i = 0; i < 2; ++i)
            dst[tid + 512 * i] = srcV[tid + 512 * i];
#pragma unroll
        for (int i = 0; i < 3; ++i)
            dst[1024 + tid + 512 * i] = srcW[tid + 512 * i];
    }
    __syncthreads();                       // the ONLY barrier

    short* S = Sp[w];
    const short* W2l = Wl + 8192;
    const int mloc = l & 15;               // chunk-within-group (MFMA B-col)
    const int koff = (l >> 4) * 8;
    float2 lt = lamT[c * NN + l];
    float sr = 0.f, si = 0.f;              // running state, f32 entire L

    const float2* stb = st ? (st + (size_t)b * LL) : nullptr;
    float wc = 0.f, bcf = 0.f;
    if (st) { wc = nw[c]; bcf = nb[c]; }

#pragma unroll 1
    for (int g = 0; g < 4; ++g) {
        const int lbase = (g * 16 + mloc) * 64 + koff;
        const bf16* xg = xrow + lbase;

        // ---- load (and optionally normalize) x fragments ----
        short8 xf0 = *(const short8*)(xg);
        short8 xf1 = *(const short8*)(xg + 32);
        if (stb) {
#pragma unroll
            for (int e = 0; e < 8; ++e) {
                float2 s0 = stb[lbase + e];
                float2 s1 = stb[lbase + 32 + e];
                float a0 = s0.y * wc, a1 = s1.y * wc;
                xf0[e] = bfbits(fmaf(frombits(xf0[e]), a0, fmaf(-s0.x, a0, bcf)));
                xf1[e] = bfbits(fmaf(frombits(xf1[e]), a1, fmaf(-s1.x, a1, bcf)));
            }
        }

        // ---- phase 1 (two 4-nf halves to cap acc pressure) ----
#pragma unroll
        for (int h = 0; h < 2; ++h) {
            f32x4 acc[4];
#pragma unroll
            for (int j = 0; j < 4; ++j) acc[j] = (f32x4){0.f, 0.f, 0.f, 0.f};
#pragma unroll
            for (int j = 0; j < 4; ++j) {
                int nf = h * 4 + j;
                short8 vf0 = *(const short8*)(&Wl[((nf * 2 + 0) * 64 + l) * 8]);
                short8 vf1 = *(const short8*)(&Wl[((nf * 2 + 1) * 64 + l) * 8]);
                acc[j] = MFMA(vf0, xf0, acc[j]);
                acc[j] = MFMA(vf1, xf1, acc[j]);
            }
#pragma unroll
            for (int j = 0; j < 4; ++j) {
                int nf = h * 4 + j;
                short4v t;
                t[0] = bfbits(acc[j][0]); t[1] = bfbits(acc[j][1]);
                t[2] = bfbits(acc[j][2]); t[3] = bfbits(acc[j][3]);
                *(short4v*)(&S[mloc * 136 + nf * 16 + (l >> 4) * 4]) = t;
            }
        }
        asm volatile("" ::: "memory");     // same-wave DS pipe is in-order

        // ---- scan: 16 private steps; Sprev replaces P in place ----
#pragma unroll
        for (int k = 0; k < 16; ++k) {
            uint pk = *(const uint*)(&S[k * 136 + 2 * l]);
            union { short2 s2; uint uu; } o;
            o.s2.x = bfbits(sr); o.s2.y = bfbits(si);
            *(uint*)(&S[k * 136 + 2 * l]) = o.uu;      // Sprev for chunk k
            float pr = __uint_as_float(pk << 16);
            float pi = __uint_as_float(pk & 0xffff0000u);
            float nr = fmaf(lt.x, sr, fmaf(-lt.y, si, pr));
            si = fmaf(lt.x, si, fmaf(lt.y, sr, pi));
            sr = nr;
        }
        asm volatile("" ::: "memory");

        // ---- phase 3: K=192 GEMM over [x | Sprev]; weights from LDS ----
        f32x4 o[4];
#pragma unroll
        for (int nf = 0; nf < 4; ++nf) o[nf] = (f32x4){0.f, 0.f, 0.f, 0.f};
#pragma unroll
        for (int ks = 0; ks < 6; ++ks) {
            short8 xf;
            if (ks == 0)      xf = xf0;
            else if (ks == 1) xf = xf1;
            else              xf = *(const short8*)(&S[mloc * 136 + (ks - 2) * 32 + koff]);
#pragma unroll
            for (int nf = 0; nf < 4; ++nf) {
                short8 wf = *(const short8*)(&W2l[((nf * 6 + ks) * 64 + l) * 8]);
                o[nf] = MFMA(wf, xf, o[nf]);
            }
        }
#pragma unroll
        for (int nf = 0; nf < 4; ++nf) {
            short4v t;
            t[0] = bfbits(o[nf][0]); t[1] = bfbits(o[nf][1]);
            t[2] = bfbits(o[nf][2]); t[3] = bfbits(o[nf][3]);
            *(short4v*)(vrow + (g * 16 + mloc) * 64 + nf * 16 + (l >> 4) * 4) = t;
        }
    }
}

// ---------------------------------------------------------------------------
// Final LayerNorm over C + head projection (fp32 out).
// ---------------------------------------------------------------------------
__global__ __launch_bounds__(256) void ln_kernel(
    const bf16* __restrict__ v,
    const float* __restrict__ w, const float* __restrict__ bta,
    const float* __restrict__ headw, const float* __restrict__ headb,
    float* __restrict__ fout)
{
    __shared__ float tile[CC][65];
    __shared__ float r1[4][64];
    __shared__ float r2[4][64];
    __shared__ float mrs[2][64];
    int b    = blockIdx.y;
    int l0   = blockIdx.x * 64;
    int lane = threadIdx.x & 63;
    int cg   = threadIdx.x >> 6;
    float sum = 0.0f, sq = 0.0f;
#pragma unroll
    for (int ci = 0; ci < 32; ++ci) {
        int c = cg * 32 + ci;
        float val = __bfloat162float(v[((size_t)b * CC + c) * LL + l0 + lane]);
        tile[c][lane] = val;
        sum += val;
        sq = fmaf(val, val, sq);
    }
    r1[cg][lane] = sum;
    r2[cg][lane] = sq;
    __syncthreads();
    if (cg == 0) {
        float s = r1[0][lane] + r1[1][lane] + r1[2][lane] + r1[3][lane];
        float q = r2[0][lane] + r2[1][lane] + r2[2][lane] + r2[3][lane];
        float mean = s * (1.0f / CC);
        float var  = q * (1.0f / CC) - mean * mean;
        mrs[0][lane] = mean;
        mrs[1][lane] = rsqrtf(var + EPSV);
    }
    __syncthreads();
    float mean = mrs[0][lane], rstd = mrs[1][lane];
    float h = 0.0f;
#pragma unroll
    for (int ci = 0; ci < 32; ++ci) {
        int c = cg * 32 + ci;
        float o = (tile[c][lane] - mean) * rstd * w[c] + bta[c];
        h = fmaf(o, headw[c], h);
    }
    __syncthreads();
    r1[cg][lane] = h;
    __syncthreads();
    if (cg == 0)
        fout[(size_t)b * LL + l0 + lane] =
            r1[0][lane] + r1[1][lane] + r1[2][lane] + r1[3][lane] + headb[0];
}

// ---------------------------------------------------------------------------
extern "C" void kernel_launch(void* const* d_in, const int* in_sizes, int n_in,
                              void* d_out, int out_size, void* d_ws, size_t ws_size,
                              hipStream_t stream)
{
    const float* x      = (const float*)d_in[0];
    const float* log_dt = (const float*)d_in[1];
    const float* A_real = (const float*)d_in[2];
    const float* A_imag = (const float*)d_in[3];
    const float* C_re   = (const float*)d_in[4];
    const float* C_im   = (const float*)d_in[5];
    const float* Dskip  = (const float*)d_in[6];
    const float* norm_w = (const float*)d_in[7];
    const float* norm_b = (const float*)d_in[8];
    const float* head_w = (const float*)d_in[9];
    const float* head_b = (const float*)d_in[10];
    float* out = (float*)d_out;

    const size_t DCN = (size_t)DEPTH_ * CC * NN;
    const size_t BCL = (size_t)BB * CC * LL;

    float2* lam  = (float2*)d_ws;
    float2* dta  = lam + DCN;
    float2* cb2  = dta + DCN;
    float2* lamT = cb2 + DCN;
    float*  Kloc = (float*)(lamT + DCN);
    bf16*   A    = (bf16*)(Kloc + (size_t)DEPTH_ * CC * 64);
    bf16*   Bb   = A + BCL;
    bf16*   Vp   = Bb + BCL;
    bf16*   W2p  = Vp + (size_t)DEPTH_ * CC * 8192;
    float2* stbuf = (float2*)(W2p + (size_t)DEPTH_ * CC * 12288);  // B*L float2

    p0_kernel<<<dim3(CC, DEPTH_), 64, 0, stream>>>(
        log_dt, A_real, A_imag, C_re, C_im, lam, dta, cb2, lamT);
    p1_kernel<<<dim3(CC, DEPTH_), 64, 0, stream>>>(cb2, lam, Kloc);
    p2v_kernel<<<(DEPTH_ * CC * 8192) / 256, 256, 0, stream>>>(dta, Vp);
    p2w_kernel<<<(DEPTH_ * CC * 12288) / 256, 256, 0, stream>>>(
        dta, cb2, Kloc, Dskip, W2p);
    transpose_kernel<<<dim3(CC / 64, LL / 64, BB), 256, 0, stream>>>(x, A);

    // d=0: A -> Bb (no input norm)
    ks_kernel<<<dim3(CC, BB / 8), 512, 0, stream>>>(
        A, Bb, Vp, W2p, lamT, nullptr, nullptr, nullptr);
    // middle layers: stats then normalized ks
    bf16* src = Bb;
    bf16* dst = A;
    for (int d = 1; d < DEPTH_; ++d) {
        stats_kernel<<<dim3(LL / 256, BB), 256, 0, stream>>>(src, stbuf);
        ks_kernel<<<dim3(CC, BB / 8), 512, 0, stream>>>(
            src, dst, Vp + (size_t)d * CC * 8192, W2p + (size_t)d * CC * 12288,
            lamT + (size_t)d * CC * NN, stbuf,
            norm_w + (d - 1) * CC, norm_b + (d - 1) * CC);
        bf16* tmp = src; src = dst; dst = tmp;
    }
    // final LN + head on v3 (= src after swap)
    ln_kernel<<<dim3(LL / 64, BB), 256, 0, stream>>>(
        src, norm_w + (DEPTH_ - 1) * CC, norm_b + (DEPTH_ - 1) * CC,
        head_w, head_b, out);
}

// Round 15
// 179.938 us; speedup vs baseline: 2.6402x; 1.0256x over previous
//
#include <hip/hip_runtime.h>
#include <hip/hip_bf16.h>

// S4D regressor, chunked-scan MFMA formulation.
// R15: REVERT to R12 (last green: LDS-staged weights, 8-wave ks, LN fused
// into next ks via stats) after the R13/R14 group-batched restructure failed
// correctness twice with a layout-sensitive error (unresolved; do not
// re-attempt without a barrier-instrumented debug variant).
// New in R15: final LN+head collapsed to ONE pass via the identity
//   out = rstd*(sum_c v_c*wh_c - mu*S1) + S2,  wh_c = nw_c*hw_c
// (three simultaneous reductions, stats-style short4 loads).
// B=32, L=4096, C=128, N=64, DEPTH=4, OUT=1.

#define BB     32
#define LL     4096
#define CC     128
#define NN     64
#define DEPTH_ 4
#define EPSV   1e-5f

typedef __attribute__((ext_vector_type(8))) short short8;
typedef __attribute__((ext_vector_type(4))) short short4v;
typedef __attribute__((ext_vector_type(4))) float f32x4;
typedef __hip_bfloat16 bf16;

#define MFMA(a, b, c) __builtin_amdgcn_mfma_f32_16x16x32_bf16(a, b, c, 0, 0, 0)

__device__ __forceinline__ bf16 tobf(float x) { return __float2bfloat16(x); }
__device__ __forceinline__ short bfbits(float x) {
    union { bf16 b; short s; } u; u.b = __float2bfloat16(x); return u.s;
}
__device__ __forceinline__ float frombits(short s) {
    return __uint_as_float(((uint)(ushort)s) << 16);
}

// ---------------------------------------------------------------------------
// P0: per (d,c,n): lam=exp(dt*A), dta=dt*A, cb2=2*C*(lam-1)/A, lamT=lam^64
// ---------------------------------------------------------------------------
__global__ __launch_bounds__(64) void p0_kernel(
    const float* __restrict__ log_dt, const float* __restrict__ A_real,
    const float* __restrict__ A_imag, const float* __restrict__ C_re,
    const float* __restrict__ C_im, float2* __restrict__ lam,
    float2* __restrict__ dta, float2* __restrict__ cb2,
    float2* __restrict__ lamT)
{
    int d = blockIdx.y, c = blockIdx.x, n = threadIdx.x;
    int idx = (d * CC + c) * NN + n;
    float dt  = expf(log_dt[d * CC + c]);
    float Ar  = -expf(A_real[idx]);
    float Ai  = A_imag[idx];
    float dtr = dt * Ar, dti = dt * Ai;
    float e   = expf(dtr);
    float lr  = e * cosf(dti), li = e * sinf(dti);
    float m    = Ar * Ar + Ai * Ai;
    float inv  = 1.0f / m;
    float numr = lr - 1.0f, numi = li;
    float br   = (numr * Ar + numi * Ai) * inv;
    float bi   = (numi * Ar - numr * Ai) * inv;
    float cre  = C_re[idx], cim = C_im[idx];
    lam[idx]  = make_float2(lr, li);
    dta[idx]  = make_float2(dtr, dti);
    cb2[idx]  = make_float2(2.0f * (cre * br - cim * bi),
                            2.0f * (cre * bi + cim * br));
    float eT = expf(64.0f * dtr);
    lamT[idx] = make_float2(eT * cosf(64.0f * dti), eT * sinf(64.0f * dti));
}

// ---------------------------------------------------------------------------
// P1: Kloc[d][c][delta] = Re sum_n cb2_n lam_n^delta   (delta = 0..63)
// ---------------------------------------------------------------------------
__global__ __launch_bounds__(64) void p1_kernel(
    const float2* __restrict__ cb2, const float2* __restrict__ lam,
    float* __restrict__ Kloc)
{
    __shared__ float st[64 * 65];
    int d = blockIdx.y, c = blockIdx.x, n = threadIdx.x;
    float2 p = cb2[(d * CC + c) * NN + n];
    float2 l = lam[(d * CC + c) * NN + n];
    for (int t = 0; t < 64; ++t) {
        st[t * 65 + n] = p.x;
        float nr = p.x * l.x - p.y * l.y;
        p.y = p.x * l.y + p.y * l.x;
        p.x = nr;
    }
    __syncthreads();
    float s = 0.0f;
#pragma unroll 16
    for (int j = 0; j < 64; ++j) s += st[n * 65 + j];
    Kloc[(d * CC + c) * 64 + n] = s;
}

// ---------------------------------------------------------------------------
// P2V: Vp packed [d][c][nf=8][ks=2][lane=64][e=8]: B[k][q]=Re/Im(lam_n^{63-k})
// ---------------------------------------------------------------------------
__global__ __launch_bounds__(256) void p2v_kernel(
    const float2* __restrict__ dta, bf16* __restrict__ Vp)
{
    int t = blockIdx.x * 256 + threadIdx.x;
    int e = t & 7, l = (t >> 3) & 63, ks = (t >> 9) & 1;
    int nf = (t >> 10) & 7, c = (t >> 13) & 127, d = t >> 20;
    int q = nf * 16 + (l & 15);
    int k = ks * 32 + (l >> 4) * 8 + e;
    int n = q >> 1;
    float2 a = dta[(d * CC + c) * NN + n];
    float p  = (float)(63 - k);
    float mag = expf(p * a.x);
    float ang = p * a.y;
    float val = (q & 1) ? mag * sinf(ang) : mag * cosf(ang);
    Vp[t] = tobf(val);
}

// ---------------------------------------------------------------------------
// P2W: W2p packed [d][c][nf=4][ks=6][lane=64][e=8]
// ---------------------------------------------------------------------------
__global__ __launch_bounds__(256) void p2w_kernel(
    const float2* __restrict__ dta, const float2* __restrict__ cb2,
    const float* __restrict__ Kloc, const float* __restrict__ Dskip,
    bf16* __restrict__ W2p)
{
    int t = blockIdx.x * 256 + threadIdx.x;
    int e = t & 7, l = (t >> 3) & 63;
    int r = t >> 9;
    int ks = r % 6; r /= 6;
    int nf = r & 3; r >>= 2;
    int c  = r & 127;
    int d  = r >> 7;
    int i = nf * 16 + (l & 15);
    int k = ks * 32 + (l >> 4) * 8 + e;
    float val;
    if (k < 64) {
        val = (k <= i) ? Kloc[(d * CC + c) * 64 + (i - k)] : 0.0f;
        if (k == i) val += Dskip[d * CC + c] + 1.0f;
    } else {
        int q = k - 64, n = q >> 1;
        float2 a  = dta[(d * CC + c) * NN + n];
        float2 cb = cb2[(d * CC + c) * NN + n];
        float p   = (float)(i + 1);
        float mag = expf(p * a.x);
        float ang = p * a.y;
        float re = mag * cosf(ang), im = mag * sinf(ang);
        float wre = cb.x * re - cb.y * im;
        float wim = cb.x * im + cb.y * re;
        val = (q & 1) ? -wim : wre;
    }
    W2p[t] = tobf(val);
}

// ---------------------------------------------------------------------------
// x [B,L,C] fp32 -> xt [B][C][L] bf16
// ---------------------------------------------------------------------------
__global__ __launch_bounds__(256) void transpose_kernel(
    const float* __restrict__ x, bf16* __restrict__ xt)
{
    __shared__ float t[64][65];
    int ct = blockIdx.x, lt = blockIdx.y, b = blockIdx.z;
    int tx = threadIdx.x & 63, ty = threadIdx.x >> 6;
    const size_t xbase = ((size_t)b * LL + (size_t)lt * 64) * CC + (size_t)ct * 64;
#pragma unroll
    for (int i = 0; i < 16; ++i)
        t[ty + 4 * i][tx] = x[xbase + (size_t)(ty + 4 * i) * CC + tx];
    __syncthreads();
    const size_t obase = ((size_t)b * CC + (size_t)ct * 64) * LL + (size_t)lt * 64;
#pragma unroll
    for (int i = 0; i < 16; ++i)
        xt[obase + (size_t)(ty + 4 * i) * LL + tx] = tobf(t[tx][ty + 4 * i]);
}

// ---------------------------------------------------------------------------
// STATS: per-(b,l) LayerNorm statistics (mean, rstd) from v [B][C][L] bf16.
// ---------------------------------------------------------------------------
__global__ __launch_bounds__(256) void stats_kernel(
    const bf16* __restrict__ v, float2* __restrict__ st)
{
    __shared__ float rs[4][256];
    __shared__ float rq[4][256];
    int b  = blockIdx.y;
    int l0 = blockIdx.x * 256;
    int lt = threadIdx.x & 63;
    int cg = threadIdx.x >> 6;
    const short* vv = (const short*)v;
    float s[4] = {0.f, 0.f, 0.f, 0.f};
    float q[4] = {0.f, 0.f, 0.f, 0.f};
#pragma unroll
    for (int ci = 0; ci < 32; ++ci) {
        int c = cg * 32 + ci;
        short4v r = *(const short4v*)(&vv[((size_t)b * CC + c) * LL + l0 + lt * 4]);
#pragma unroll
        for (int j = 0; j < 4; ++j) {
            float f = frombits(r[j]);
            s[j] += f;
            q[j] = fmaf(f, f, q[j]);
        }
    }
#pragma unroll
    for (int j = 0; j < 4; ++j) {
        rs[cg][lt * 4 + j] = s[j];
        rq[cg][lt * 4 + j] = q[j];
    }
    __syncthreads();
    if (cg == 0) {
#pragma unroll
        for (int j = 0; j < 4; ++j) {
            int li = lt * 4 + j;
            float ts = rs[0][li] + rs[1][li] + rs[2][li] + rs[3][li];
            float tq = rq[0][li] + rq[1][li] + rq[2][li] + rq[3][li];
            float mean = ts * (1.0f / CC);
            float var  = tq * (1.0f / CC) - mean * mean;
            st[(size_t)b * LL + l0 + li] = make_float2(mean, rsqrtf(var + EPSV));
        }
    }
}

// ---------------------------------------------------------------------------
// KS: block = (c, 8 b's), 512 threads. Weights (40 KB) staged in LDS once.
// If st != nullptr, x-fragments are LayerNorm-normalized on load:
//   xn = f*a + (beta - mu*a),  a = rstd * w[c]   (w[c],beta[c] block-scalar).
// ---------------------------------------------------------------------------
__global__ __launch_bounds__(512) void ks_kernel(
    const bf16* __restrict__ u, bf16* __restrict__ v,
    const bf16* __restrict__ Vp, const bf16* __restrict__ W2p,
    const float2* __restrict__ lamT, const float2* __restrict__ st,
    const float* __restrict__ nw, const float* __restrict__ nb)
{
    const int c  = blockIdx.x;             // channel owned by this block
    const int w  = threadIdx.x >> 6;       // wave 0..7 -> b = bg*8+w
    const int l  = threadIdx.x & 63;       // lane: MFMA lane AND mode index n
    const int b  = blockIdx.y * 8 + w;
    const int bc = b * CC + c;
    const bf16* xrow = u + (size_t)bc * LL;
    bf16*       vrow = v + (size_t)bc * LL;

    __shared__ short Wl[8192 + 12288];     // Vp(16KB) + W2p(24KB) = 40 KB
    __shared__ short Sp[8][16 * 136];      // per-wave 4.35 KB scan slice

    // ---- stage weights: 2560 x uint4 across 512 threads, one barrier ----
    {
        uint4*       dst  = (uint4*)Wl;
        const uint4* srcV = (const uint4*)(Vp  + (size_t)c * 8192);
        const uint4* srcW = (const uint4*)(W2p + (size_t)c * 12288);
        int tid = threadIdx.x;
#pragma unroll
        for (int i = 0; i < 2; ++i)
            dst[tid + 512 * i] = srcV[tid + 512 * i];
#pragma unroll
        for (int i = 0; i < 3; ++i)
            dst[1024 + tid + 512 * i] = srcW[tid + 512 * i];
    }
    __syncthreads();                       // the ONLY barrier

    short* S = Sp[w];
    const short* W2l = Wl + 8192;
    const int mloc = l & 15;               // chunk-within-group (MFMA B-col)
    const int koff = (l >> 4) * 8;
    float2 lt = lamT[c * NN + l];
    float sr = 0.f, si = 0.f;              // running state, f32 entire L

    const float2* stb = st ? (st + (size_t)b * LL) : nullptr;
    float wc = 0.f, bcf = 0.f;
    if (st) { wc = nw[c]; bcf = nb[c]; }

#pragma unroll 1
    for (int g = 0; g < 4; ++g) {
        const int lbase = (g * 16 + mloc) * 64 + koff;
        const bf16* xg = xrow + lbase;

        // ---- load (and optionally normalize) x fragments ----
        short8 xf0 = *(const short8*)(xg);
        short8 xf1 = *(const short8*)(xg + 32);
        if (stb) {
#pragma unroll
            for (int e = 0; e < 8; ++e) {
                float2 s0 = stb[lbase + e];
                float2 s1 = stb[lbase + 32 + e];
                float a0 = s0.y * wc, a1 = s1.y * wc;
                xf0[e] = bfbits(fmaf(frombits(xf0[e]), a0, fmaf(-s0.x, a0, bcf)));
                xf1[e] = bfbits(fmaf(frombits(xf1[e]), a1, fmaf(-s1.x, a1, bcf)));
            }
        }

        // ---- phase 1 (two 4-nf halves to cap acc pressure) ----
#pragma unroll
        for (int h = 0; h < 2; ++h) {
            f32x4 acc[4];
#pragma unroll
            for (int j = 0; j < 4; ++j) acc[j] = (f32x4){0.f, 0.f, 0.f, 0.f};
#pragma unroll
            for (int j = 0; j < 4; ++j) {
                int nf = h * 4 + j;
                short8 vf0 = *(const short8*)(&Wl[((nf * 2 + 0) * 64 + l) * 8]);
                short8 vf1 = *(const short8*)(&Wl[((nf * 2 + 1) * 64 + l) * 8]);
                acc[j] = MFMA(vf0, xf0, acc[j]);
                acc[j] = MFMA(vf1, xf1, acc[j]);
            }
#pragma unroll
            for (int j = 0; j < 4; ++j) {
                int nf = h * 4 + j;
                short4v t;
                t[0] = bfbits(acc[j][0]); t[1] = bfbits(acc[j][1]);
                t[2] = bfbits(acc[j][2]); t[3] = bfbits(acc[j][3]);
                *(short4v*)(&S[mloc * 136 + nf * 16 + (l >> 4) * 4]) = t;
            }
        }
        asm volatile("" ::: "memory");     // same-wave DS pipe is in-order

        // ---- scan: 16 private steps; Sprev replaces P in place ----
#pragma unroll
        for (int k = 0; k < 16; ++k) {
            uint pk = *(const uint*)(&S[k * 136 + 2 * l]);
            union { short2 s2; uint uu; } o;
            o.s2.x = bfbits(sr); o.s2.y = bfbits(si);
            *(uint*)(&S[k * 136 + 2 * l]) = o.uu;      // Sprev for chunk k
            float pr = __uint_as_float(pk << 16);
            float pi = __uint_as_float(pk & 0xffff0000u);
            float nr = fmaf(lt.x, sr, fmaf(-lt.y, si, pr));
            si = fmaf(lt.x, si, fmaf(lt.y, sr, pi));
            sr = nr;
        }
        asm volatile("" ::: "memory");

        // ---- phase 3: K=192 GEMM over [x | Sprev]; weights from LDS ----
        f32x4 o[4];
#pragma unroll
        for (int nf = 0; nf < 4; ++nf) o[nf] = (f32x4){0.f, 0.f, 0.f, 0.f};
#pragma unroll
        for (int ks = 0; ks < 6; ++ks) {
            short8 xf;
            if (ks == 0)      xf = xf0;
            else if (ks == 1) xf = xf1;
            else              xf = *(const short8*)(&S[mloc * 136 + (ks - 2) * 32 + koff]);
#pragma unroll
            for (int nf = 0; nf < 4; ++nf) {
                short8 wf = *(const short8*)(&W2l[((nf * 6 + ks) * 64 + l) * 8]);
                o[nf] = MFMA(wf, xf, o[nf]);
            }
        }
#pragma unroll
        for (int nf = 0; nf < 4; ++nf) {
            short4v t;
            t[0] = bfbits(o[nf][0]); t[1] = bfbits(o[nf][1]);
            t[2] = bfbits(o[nf][2]); t[3] = bfbits(o[nf][3]);
            *(short4v*)(vrow + (g * 16 + mloc) * 64 + nf * 16 + (l >> 4) * 4) = t;
        }
    }
}

// ---------------------------------------------------------------------------
// LN3: final LayerNorm + head in ONE pass over v.
//   out[b,l] = rstd*( sum_c v*wh_c - mu*S1 ) + S2
//   wh_c = nw_c*hw_c;  S1 = sum wh_c;  S2 = sum beta_c*hw_c + head_b.
// stats-style short4 loads; three simultaneous reductions.
// ---------------------------------------------------------------------------
__global__ __launch_bounds__(256) void ln3_kernel(
    const bf16* __restrict__ v,
    const float* __restrict__ w, const float* __restrict__ bta,
    const float* __restrict__ headw, const float* __restrict__ headb,
    float* __restrict__ fout)
{
    __shared__ float rs[4][256];
    __shared__ float rq[4][256];
    __shared__ float rh[4][256];
    __shared__ float r1s[4];
    __shared__ float r2s[4];
    int b  = blockIdx.y;
    int l0 = blockIdx.x * 256;
    int lt = threadIdx.x & 63;
    int cg = threadIdx.x >> 6;
    const short* vv = (const short*)v;
    float s[4] = {0.f, 0.f, 0.f, 0.f};
    float q[4] = {0.f, 0.f, 0.f, 0.f};
    float h[4] = {0.f, 0.f, 0.f, 0.f};
    float ps1 = 0.f, ps2 = 0.f;
#pragma unroll
    for (int ci = 0; ci < 32; ++ci) {
        int c = cg * 32 + ci;
        float hwc = headw[c];
        float whc = w[c] * hwc;
        ps1 += whc;
        ps2 = fmaf(bta[c], hwc, ps2);
        short4v r = *(const short4v*)(&vv[((size_t)b * CC + c) * LL + l0 + lt * 4]);
#pragma unroll
        for (int j = 0; j < 4; ++j) {
            float f = frombits(r[j]);
            s[j] += f;
            q[j] = fmaf(f, f, q[j]);
            h[j] = fmaf(f, whc, h[j]);
        }
    }
#pragma unroll
    for (int j = 0; j < 4; ++j) {
        rs[cg][lt * 4 + j] = s[j];
        rq[cg][lt * 4 + j] = q[j];
        rh[cg][lt * 4 + j] = h[j];
    }
    if (lt == 0) { r1s[cg] = ps1; r2s[cg] = ps2; }
    __syncthreads();
    if (cg == 0) {
        float S1 = r1s[0] + r1s[1] + r1s[2] + r1s[3];
        float S2 = r2s[0] + r2s[1] + r2s[2] + r2s[3] + headb[0];
#pragma unroll
        for (int j = 0; j < 4; ++j) {
            int li = lt * 4 + j;
            float ts = rs[0][li] + rs[1][li] + rs[2][li] + rs[3][li];
            float tq = rq[0][li] + rq[1][li] + rq[2][li] + rq[3][li];
            float th = rh[0][li] + rh[1][li] + rh[2][li] + rh[3][li];
            float mean = ts * (1.0f / CC);
            float var  = tq * (1.0f / CC) - mean * mean;
            float rstd = rsqrtf(var + EPSV);
            fout[(size_t)b * LL + l0 + li] = rstd * (th - mean * S1) + S2;
        }
    }
}

// ---------------------------------------------------------------------------
extern "C" void kernel_launch(void* const* d_in, const int* in_sizes, int n_in,
                              void* d_out, int out_size, void* d_ws, size_t ws_size,
                              hipStream_t stream)
{
    const float* x      = (const float*)d_in[0];
    const float* log_dt = (const float*)d_in[1];
    const float* A_real = (const float*)d_in[2];
    const float* A_imag = (const float*)d_in[3];
    const float* C_re   = (const float*)d_in[4];
    const float* C_im   = (const float*)d_in[5];
    const float* Dskip  = (const float*)d_in[6];
    const float* norm_w = (const float*)d_in[7];
    const float* norm_b = (const float*)d_in[8];
    const float* head_w = (const float*)d_in[9];
    const float* head_b = (const float*)d_in[10];
    float* out = (float*)d_out;

    const size_t DCN = (size_t)DEPTH_ * CC * NN;
    const size_t BCL = (size_t)BB * CC * LL;

    float2* lam  = (float2*)d_ws;
    float2* dta  = lam + DCN;
    float2* cb2  = dta + DCN;
    float2* lamT = cb2 + DCN;
    float*  Kloc = (float*)(lamT + DCN);
    bf16*   A    = (bf16*)(Kloc + (size_t)DEPTH_ * CC * 64);
    bf16*   Bb   = A + BCL;
    bf16*   Vp   = Bb + BCL;
    bf16*   W2p  = Vp + (size_t)DEPTH_ * CC * 8192;
    float2* stbuf = (float2*)(W2p + (size_t)DEPTH_ * CC * 12288);  // B*L float2

    p0_kernel<<<dim3(CC, DEPTH_), 64, 0, stream>>>(
        log_dt, A_real, A_imag, C_re, C_im, lam, dta, cb2, lamT);
    p1_kernel<<<dim3(CC, DEPTH_), 64, 0, stream>>>(cb2, lam, Kloc);
    p2v_kernel<<<(DEPTH_ * CC * 8192) / 256, 256, 0, stream>>>(dta, Vp);
    p2w_kernel<<<(DEPTH_ * CC * 12288) / 256, 256, 0, stream>>>(
        dta, cb2, Kloc, Dskip, W2p);
    transpose_kernel<<<dim3(CC / 64, LL / 64, BB), 256, 0, stream>>>(x, A);

    // d=0: A -> Bb (no input norm)
    ks_kernel<<<dim3(CC, BB / 8), 512, 0, stream>>>(
        A, Bb, Vp, W2p, lamT, nullptr, nullptr, nullptr);
    // middle layers: stats then normalized ks
    bf16* src = Bb;
    bf16* dst = A;
    for (int d = 1; d < DEPTH_; ++d) {
        stats_kernel<<<dim3(LL / 256, BB), 256, 0, stream>>>(src, stbuf);
        ks_kernel<<<dim3(CC, BB / 8), 512, 0, stream>>>(
            src, dst, Vp + (size_t)d * CC * 8192, W2p + (size_t)d * CC * 12288,
            lamT + (size_t)d * CC * NN, stbuf,
            norm_w + (d - 1) * CC, norm_b + (d - 1) * CC);
        bf16* tmp = src; src = dst; dst = tmp;
    }
    // final LN + head, one pass
    ln3_kernel<<<dim3(LL / 256, BB), 256, 0, stream>>>(
        src, norm_w + (DEPTH_ - 1) * CC, norm_b + (DEPTH_ - 1) * CC,
        head_w, head_b, out);
}

// Round 16
// 178.973 us; speedup vs baseline: 2.6544x; 1.0054x over previous
//
#include <hip/hip_runtime.h>
#include <hip/hip_bf16.h>

// S4D regressor, chunked-scan MFMA formulation.
// R16: R15 (green, 179.9 us) + ks micro-opts, structure untouched:
//  (a) cross-group xf prefetch — next group's 2 global x loads issued after
//      phase-1's fence so their ~600cy latency hides under scan+phase3;
//  (b) normalize stat loads vectorized: 16x8B float2 -> 8x16B float4.
// Both bit-identical numerics. No launch-bounds min-waves (spill trap x3).
// B=32, L=4096, C=128, N=64, DEPTH=4, OUT=1.

#define BB     32
#define LL     4096
#define CC     128
#define NN     64
#define DEPTH_ 4
#define EPSV   1e-5f

typedef __attribute__((ext_vector_type(8))) short short8;
typedef __attribute__((ext_vector_type(4))) short short4v;
typedef __attribute__((ext_vector_type(4))) float f32x4;
typedef __hip_bfloat16 bf16;

#define MFMA(a, b, c) __builtin_amdgcn_mfma_f32_16x16x32_bf16(a, b, c, 0, 0, 0)

__device__ __forceinline__ bf16 tobf(float x) { return __float2bfloat16(x); }
__device__ __forceinline__ short bfbits(float x) {
    union { bf16 b; short s; } u; u.b = __float2bfloat16(x); return u.s;
}
__device__ __forceinline__ float frombits(short s) {
    return __uint_as_float(((uint)(ushort)s) << 16);
}

// ---------------------------------------------------------------------------
// P0: per (d,c,n): lam=exp(dt*A), dta=dt*A, cb2=2*C*(lam-1)/A, lamT=lam^64
// ---------------------------------------------------------------------------
__global__ __launch_bounds__(64) void p0_kernel(
    const float* __restrict__ log_dt, const float* __restrict__ A_real,
    const float* __restrict__ A_imag, const float* __restrict__ C_re,
    const float* __restrict__ C_im, float2* __restrict__ lam,
    float2* __restrict__ dta, float2* __restrict__ cb2,
    float2* __restrict__ lamT)
{
    int d = blockIdx.y, c = blockIdx.x, n = threadIdx.x;
    int idx = (d * CC + c) * NN + n;
    float dt  = expf(log_dt[d * CC + c]);
    float Ar  = -expf(A_real[idx]);
    float Ai  = A_imag[idx];
    float dtr = dt * Ar, dti = dt * Ai;
    float e   = expf(dtr);
    float lr  = e * cosf(dti), li = e * sinf(dti);
    float m    = Ar * Ar + Ai * Ai;
    float inv  = 1.0f / m;
    float numr = lr - 1.0f, numi = li;
    float br   = (numr * Ar + numi * Ai) * inv;
    float bi   = (numi * Ar - numr * Ai) * inv;
    float cre  = C_re[idx], cim = C_im[idx];
    lam[idx]  = make_float2(lr, li);
    dta[idx]  = make_float2(dtr, dti);
    cb2[idx]  = make_float2(2.0f * (cre * br - cim * bi),
                            2.0f * (cre * bi + cim * br));
    float eT = expf(64.0f * dtr);
    lamT[idx] = make_float2(eT * cosf(64.0f * dti), eT * sinf(64.0f * dti));
}

// ---------------------------------------------------------------------------
// P1: Kloc[d][c][delta] = Re sum_n cb2_n lam_n^delta   (delta = 0..63)
// ---------------------------------------------------------------------------
__global__ __launch_bounds__(64) void p1_kernel(
    const float2* __restrict__ cb2, const float2* __restrict__ lam,
    float* __restrict__ Kloc)
{
    __shared__ float st[64 * 65];
    int d = blockIdx.y, c = blockIdx.x, n = threadIdx.x;
    float2 p = cb2[(d * CC + c) * NN + n];
    float2 l = lam[(d * CC + c) * NN + n];
    for (int t = 0; t < 64; ++t) {
        st[t * 65 + n] = p.x;
        float nr = p.x * l.x - p.y * l.y;
        p.y = p.x * l.y + p.y * l.x;
        p.x = nr;
    }
    __syncthreads();
    float s = 0.0f;
#pragma unroll 16
    for (int j = 0; j < 64; ++j) s += st[n * 65 + j];
    Kloc[(d * CC + c) * 64 + n] = s;
}

// ---------------------------------------------------------------------------
// P2V: Vp packed [d][c][nf=8][ks=2][lane=64][e=8]: B[k][q]=Re/Im(lam_n^{63-k})
// ---------------------------------------------------------------------------
__global__ __launch_bounds__(256) void p2v_kernel(
    const float2* __restrict__ dta, bf16* __restrict__ Vp)
{
    int t = blockIdx.x * 256 + threadIdx.x;
    int e = t & 7, l = (t >> 3) & 63, ks = (t >> 9) & 1;
    int nf = (t >> 10) & 7, c = (t >> 13) & 127, d = t >> 20;
    int q = nf * 16 + (l & 15);
    int k = ks * 32 + (l >> 4) * 8 + e;
    int n = q >> 1;
    float2 a = dta[(d * CC + c) * NN + n];
    float p  = (float)(63 - k);
    float mag = expf(p * a.x);
    float ang = p * a.y;
    float val = (q & 1) ? mag * sinf(ang) : mag * cosf(ang);
    Vp[t] = tobf(val);
}

// ---------------------------------------------------------------------------
// P2W: W2p packed [d][c][nf=4][ks=6][lane=64][e=8]
// ---------------------------------------------------------------------------
__global__ __launch_bounds__(256) void p2w_kernel(
    const float2* __restrict__ dta, const float2* __restrict__ cb2,
    const float* __restrict__ Kloc, const float* __restrict__ Dskip,
    bf16* __restrict__ W2p)
{
    int t = blockIdx.x * 256 + threadIdx.x;
    int e = t & 7, l = (t >> 3) & 63;
    int r = t >> 9;
    int ks = r % 6; r /= 6;
    int nf = r & 3; r >>= 2;
    int c  = r & 127;
    int d  = r >> 7;
    int i = nf * 16 + (l & 15);
    int k = ks * 32 + (l >> 4) * 8 + e;
    float val;
    if (k < 64) {
        val = (k <= i) ? Kloc[(d * CC + c) * 64 + (i - k)] : 0.0f;
        if (k == i) val += Dskip[d * CC + c] + 1.0f;
    } else {
        int q = k - 64, n = q >> 1;
        float2 a  = dta[(d * CC + c) * NN + n];
        float2 cb = cb2[(d * CC + c) * NN + n];
        float p   = (float)(i + 1);
        float mag = expf(p * a.x);
        float ang = p * a.y;
        float re = mag * cosf(ang), im = mag * sinf(ang);
        float wre = cb.x * re - cb.y * im;
        float wim = cb.x * im + cb.y * re;
        val = (q & 1) ? -wim : wre;
    }
    W2p[t] = tobf(val);
}

// ---------------------------------------------------------------------------
// x [B,L,C] fp32 -> xt [B][C][L] bf16
// ---------------------------------------------------------------------------
__global__ __launch_bounds__(256) void transpose_kernel(
    const float* __restrict__ x, bf16* __restrict__ xt)
{
    __shared__ float t[64][65];
    int ct = blockIdx.x, lt = blockIdx.y, b = blockIdx.z;
    int tx = threadIdx.x & 63, ty = threadIdx.x >> 6;
    const size_t xbase = ((size_t)b * LL + (size_t)lt * 64) * CC + (size_t)ct * 64;
#pragma unroll
    for (int i = 0; i < 16; ++i)
        t[ty + 4 * i][tx] = x[xbase + (size_t)(ty + 4 * i) * CC + tx];
    __syncthreads();
    const size_t obase = ((size_t)b * CC + (size_t)ct * 64) * LL + (size_t)lt * 64;
#pragma unroll
    for (int i = 0; i < 16; ++i)
        xt[obase + (size_t)(ty + 4 * i) * LL + tx] = tobf(t[tx][ty + 4 * i]);
}

// ---------------------------------------------------------------------------
// STATS: per-(b,l) LayerNorm statistics (mean, rstd) from v [B][C][L] bf16.
// ---------------------------------------------------------------------------
__global__ __launch_bounds__(256) void stats_kernel(
    const bf16* __restrict__ v, float2* __restrict__ st)
{
    __shared__ float rs[4][256];
    __shared__ float rq[4][256];
    int b  = blockIdx.y;
    int l0 = blockIdx.x * 256;
    int lt = threadIdx.x & 63;
    int cg = threadIdx.x >> 6;
    const short* vv = (const short*)v;
    float s[4] = {0.f, 0.f, 0.f, 0.f};
    float q[4] = {0.f, 0.f, 0.f, 0.f};
#pragma unroll
    for (int ci = 0; ci < 32; ++ci) {
        int c = cg * 32 + ci;
        short4v r = *(const short4v*)(&vv[((size_t)b * CC + c) * LL + l0 + lt * 4]);
#pragma unroll
        for (int j = 0; j < 4; ++j) {
            float f = frombits(r[j]);
            s[j] += f;
            q[j] = fmaf(f, f, q[j]);
        }
    }
#pragma unroll
    for (int j = 0; j < 4; ++j) {
        rs[cg][lt * 4 + j] = s[j];
        rq[cg][lt * 4 + j] = q[j];
    }
    __syncthreads();
    if (cg == 0) {
#pragma unroll
        for (int j = 0; j < 4; ++j) {
            int li = lt * 4 + j;
            float ts = rs[0][li] + rs[1][li] + rs[2][li] + rs[3][li];
            float tq = rq[0][li] + rq[1][li] + rq[2][li] + rq[3][li];
            float mean = ts * (1.0f / CC);
            float var  = tq * (1.0f / CC) - mean * mean;
            st[(size_t)b * LL + l0 + li] = make_float2(mean, rsqrtf(var + EPSV));
        }
    }
}

// ---------------------------------------------------------------------------
// KS: block = (c, 8 b's), 512 threads. Weights (40 KB) staged in LDS once.
// Normalize (if st): xn = f*a + (beta - mu*a), a = rstd*w[c]; stat loads as
// float4. Next group's x fragments prefetched after phase-1's fence.
// ---------------------------------------------------------------------------
__global__ __launch_bounds__(512) void ks_kernel(
    const bf16* __restrict__ u, bf16* __restrict__ v,
    const bf16* __restrict__ Vp, const bf16* __restrict__ W2p,
    const float2* __restrict__ lamT, const float2* __restrict__ st,
    const float* __restrict__ nw, const float* __restrict__ nb)
{
    const int c  = blockIdx.x;             // channel owned by this block
    const int w  = threadIdx.x >> 6;       // wave 0..7 -> b = bg*8+w
    const int l  = threadIdx.x & 63;       // lane: MFMA lane AND mode index n
    const int b  = blockIdx.y * 8 + w;
    const int bc = b * CC + c;
    const bf16* xrow = u + (size_t)bc * LL;
    bf16*       vrow = v + (size_t)bc * LL;

    __shared__ short Wl[8192 + 12288];     // Vp(16KB) + W2p(24KB) = 40 KB
    __shared__ short Sp[8][16 * 136];      // per-wave 4.35 KB scan slice

    // ---- stage weights: 2560 x uint4 across 512 threads, one barrier ----
    {
        uint4*       dst  = (uint4*)Wl;
        const uint4* srcV = (const uint4*)(Vp  + (size_t)c * 8192);
        const uint4* srcW = (const uint4*)(W2p + (size_t)c * 12288);
        int tid = threadIdx.x;
#pragma unroll
        for (int i = 0; i < 2; ++i)
            dst[tid + 512 * i] = srcV[tid + 512 * i];
#pragma unroll
        for (int i = 0; i < 3; ++i)
            dst[1024 + tid + 512 * i] = srcW[tid + 512 * i];
    }
    __syncthreads();                       // the ONLY barrier

    short* S = Sp[w];
    const short* W2l = Wl + 8192;
    const int mloc = l & 15;               // chunk-within-group (MFMA B-col)
    const int koff = (l >> 4) * 8;
    float2 lt = lamT[c * NN + l];
    float sr = 0.f, si = 0.f;              // running state, f32 entire L

    const float2* stb = st ? (st + (size_t)b * LL) : nullptr;
    float wc = 0.f, bcf = 0.f;
    if (st) { wc = nw[c]; bcf = nb[c]; }

    // ---- prefetch group 0's raw x fragments ----
    short8 xf0 = *(const short8*)(xrow + mloc * 64 + koff);
    short8 xf1 = *(const short8*)(xrow + mloc * 64 + koff + 32);

#pragma unroll 1
    for (int g = 0; g < 4; ++g) {
        const int lbase = (g * 16 + mloc) * 64 + koff;

        // ---- normalize current fragments (float4 stat loads) ----
        if (stb) {
            const float4* sq0 = (const float4*)(stb + lbase);
            const float4* sq1 = (const float4*)(stb + lbase + 32);
#pragma unroll
            for (int i = 0; i < 4; ++i) {
                float4 p0 = sq0[i], p1 = sq1[i];
                float a00 = p0.y * wc, a01 = p0.w * wc;
                float a10 = p1.y * wc, a11 = p1.w * wc;
                xf0[2 * i]     = bfbits(fmaf(frombits(xf0[2 * i]),     a00, fmaf(-p0.x, a00, bcf)));
                xf0[2 * i + 1] = bfbits(fmaf(frombits(xf0[2 * i + 1]), a01, fmaf(-p0.z, a01, bcf)));
                xf1[2 * i]     = bfbits(fmaf(frombits(xf1[2 * i]),     a10, fmaf(-p1.x, a10, bcf)));
                xf1[2 * i + 1] = bfbits(fmaf(frombits(xf1[2 * i + 1]), a11, fmaf(-p1.z, a11, bcf)));
            }
        }

        // ---- phase 1 (two 4-nf halves to cap acc pressure) ----
#pragma unroll
        for (int h = 0; h < 2; ++h) {
            f32x4 acc[4];
#pragma unroll
            for (int j = 0; j < 4; ++j) acc[j] = (f32x4){0.f, 0.f, 0.f, 0.f};
#pragma unroll
            for (int j = 0; j < 4; ++j) {
                int nf = h * 4 + j;
                short8 vf0 = *(const short8*)(&Wl[((nf * 2 + 0) * 64 + l) * 8]);
                short8 vf1 = *(const short8*)(&Wl[((nf * 2 + 1) * 64 + l) * 8]);
                acc[j] = MFMA(vf0, xf0, acc[j]);
                acc[j] = MFMA(vf1, xf1, acc[j]);
            }
#pragma unroll
            for (int j = 0; j < 4; ++j) {
                int nf = h * 4 + j;
                short4v t;
                t[0] = bfbits(acc[j][0]); t[1] = bfbits(acc[j][1]);
                t[2] = bfbits(acc[j][2]); t[3] = bfbits(acc[j][3]);
                *(short4v*)(&S[mloc * 136 + nf * 16 + (l >> 4) * 4]) = t;
            }
        }
        asm volatile("" ::: "memory");     // same-wave DS pipe is in-order

        // ---- prefetch next group's raw x fragments (covers scan+phase3) ----
        const int gn = (g < 3) ? g + 1 : 3;
        const int lbn = (gn * 16 + mloc) * 64 + koff;
        short8 nxf0 = *(const short8*)(xrow + lbn);
        short8 nxf1 = *(const short8*)(xrow + lbn + 32);

        // ---- scan: 16 private steps; Sprev replaces P in place ----
#pragma unroll
        for (int k = 0; k < 16; ++k) {
            uint pk = *(const uint*)(&S[k * 136 + 2 * l]);
            union { short2 s2; uint uu; } o;
            o.s2.x = bfbits(sr); o.s2.y = bfbits(si);
            *(uint*)(&S[k * 136 + 2 * l]) = o.uu;      // Sprev for chunk k
            float pr = __uint_as_float(pk << 16);
            float pi = __uint_as_float(pk & 0xffff0000u);
            float nr = fmaf(lt.x, sr, fmaf(-lt.y, si, pr));
            si = fmaf(lt.x, si, fmaf(lt.y, sr, pi));
            sr = nr;
        }
        asm volatile("" ::: "memory");

        // ---- phase 3: K=192 GEMM over [x | Sprev]; weights from LDS ----
        f32x4 o[4];
#pragma unroll
        for (int nf = 0; nf < 4; ++nf) o[nf] = (f32x4){0.f, 0.f, 0.f, 0.f};
#pragma unroll
        for (int ks = 0; ks < 6; ++ks) {
            short8 xf;
            if (ks == 0)      xf = xf0;
            else if (ks == 1) xf = xf1;
            else              xf = *(const short8*)(&S[mloc * 136 + (ks - 2) * 32 + koff]);
#pragma unroll
            for (int nf = 0; nf < 4; ++nf) {
                short8 wf = *(const short8*)(&W2l[((nf * 6 + ks) * 64 + l) * 8]);
                o[nf] = MFMA(wf, xf, o[nf]);
            }
        }
#pragma unroll
        for (int nf = 0; nf < 4; ++nf) {
            short4v t;
            t[0] = bfbits(o[nf][0]); t[1] = bfbits(o[nf][1]);
            t[2] = bfbits(o[nf][2]); t[3] = bfbits(o[nf][3]);
            *(short4v*)(vrow + (g * 16 + mloc) * 64 + nf * 16 + (l >> 4) * 4) = t;
        }

        xf0 = nxf0;                        // rotate prefetched fragments
        xf1 = nxf1;
    }
}

// ---------------------------------------------------------------------------
// LN3: final LayerNorm + head in ONE pass over v.
//   out[b,l] = rstd*( sum_c v*wh_c - mu*S1 ) + S2
// ---------------------------------------------------------------------------
__global__ __launch_bounds__(256) void ln3_kernel(
    const bf16* __restrict__ v,
    const float* __restrict__ w, const float* __restrict__ bta,
    const float* __restrict__ headw, const float* __restrict__ headb,
    float* __restrict__ fout)
{
    __shared__ float rs[4][256];
    __shared__ float rq[4][256];
    __shared__ float rh[4][256];
    __shared__ float r1s[4];
    __shared__ float r2s[4];
    int b  = blockIdx.y;
    int l0 = blockIdx.x * 256;
    int lt = threadIdx.x & 63;
    int cg = threadIdx.x >> 6;
    const short* vv = (const short*)v;
    float s[4] = {0.f, 0.f, 0.f, 0.f};
    float q[4] = {0.f, 0.f, 0.f, 0.f};
    float h[4] = {0.f, 0.f, 0.f, 0.f};
    float ps1 = 0.f, ps2 = 0.f;
#pragma unroll
    for (int ci = 0; ci < 32; ++ci) {
        int c = cg * 32 + ci;
        float hwc = headw[c];
        float whc = w[c] * hwc;
        ps1 += whc;
        ps2 = fmaf(bta[c], hwc, ps2);
        short4v r = *(const short4v*)(&vv[((size_t)b * CC + c) * LL + l0 + lt * 4]);
#pragma unroll
        for (int j = 0; j < 4; ++j) {
            float f = frombits(r[j]);
            s[j] += f;
            q[j] = fmaf(f, f, q[j]);
            h[j] = fmaf(f, whc, h[j]);
        }
    }
#pragma unroll
    for (int j = 0; j < 4; ++j) {
        rs[cg][lt * 4 + j] = s[j];
        rq[cg][lt * 4 + j] = q[j];
        rh[cg][lt * 4 + j] = h[j];
    }
    if (lt == 0) { r1s[cg] = ps1; r2s[cg] = ps2; }
    __syncthreads();
    if (cg == 0) {
        float S1 = r1s[0] + r1s[1] + r1s[2] + r1s[3];
        float S2 = r2s[0] + r2s[1] + r2s[2] + r2s[3] + headb[0];
#pragma unroll
        for (int j = 0; j < 4; ++j) {
            int li = lt * 4 + j;
            float ts = rs[0][li] + rs[1][li] + rs[2][li] + rs[3][li];
            float tq = rq[0][li] + rq[1][li] + rq[2][li] + rq[3][li];
            float th = rh[0][li] + rh[1][li] + rh[2][li] + rh[3][li];
            float mean = ts * (1.0f / CC);
            float var  = tq * (1.0f / CC) - mean * mean;
            float rstd = rsqrtf(var + EPSV);
            fout[(size_t)b * LL + l0 + li] = rstd * (th - mean * S1) + S2;
        }
    }
}

// ---------------------------------------------------------------------------
extern "C" void kernel_launch(void* const* d_in, const int* in_sizes, int n_in,
                              void* d_out, int out_size, void* d_ws, size_t ws_size,
                              hipStream_t stream)
{
    const float* x      = (const float*)d_in[0];
    const float* log_dt = (const float*)d_in[1];
    const float* A_real = (const float*)d_in[2];
    const float* A_imag = (const float*)d_in[3];
    const float* C_re   = (const float*)d_in[4];
    const float* C_im   = (const float*)d_in[5];
    const float* Dskip  = (const float*)d_in[6];
    const float* norm_w = (const float*)d_in[7];
    const float* norm_b = (const float*)d_in[8];
    const float* head_w = (const float*)d_in[9];
    const float* head_b = (const float*)d_in[10];
    float* out = (float*)d_out;

    const size_t DCN = (size_t)DEPTH_ * CC * NN;
    const size_t BCL = (size_t)BB * CC * LL;

    float2* lam  = (float2*)d_ws;
    float2* dta  = lam + DCN;
    float2* cb2  = dta + DCN;
    float2* lamT = cb2 + DCN;
    float*  Kloc = (float*)(lamT + DCN);
    bf16*   A    = (bf16*)(Kloc + (size_t)DEPTH_ * CC * 64);
    bf16*   Bb   = A + BCL;
    bf16*   Vp   = Bb + BCL;
    bf16*   W2p  = Vp + (size_t)DEPTH_ * CC * 8192;
    float2* stbuf = (float2*)(W2p + (size_t)DEPTH_ * CC * 12288);  // B*L float2

    p0_kernel<<<dim3(CC, DEPTH_), 64, 0, stream>>>(
        log_dt, A_real, A_imag, C_re, C_im, lam, dta, cb2, lamT);
    p1_kernel<<<dim3(CC, DEPTH_), 64, 0, stream>>>(cb2, lam, Kloc);
    p2v_kernel<<<(DEPTH_ * CC * 8192) / 256, 256, 0, stream>>>(dta, Vp);
    p2w_kernel<<<(DEPTH_ * CC * 12288) / 256, 256, 0, stream>>>(
        dta, cb2, Kloc, Dskip, W2p);
    transpose_kernel<<<dim3(CC / 64, LL / 64, BB), 256, 0, stream>>>(x, A);

    // d=0: A -> Bb (no input norm)
    ks_kernel<<<dim3(CC, BB / 8), 512, 0, stream>>>(
        A, Bb, Vp, W2p, lamT, nullptr, nullptr, nullptr);
    // middle layers: stats then normalized ks
    bf16* src = Bb;
    bf16* dst = A;
    for (int d = 1; d < DEPTH_; ++d) {
        stats_kernel<<<dim3(LL / 256, BB), 256, 0, stream>>>(src, stbuf);
        ks_kernel<<<dim3(CC, BB / 8), 512, 0, stream>>>(
            src, dst, Vp + (size_t)d * CC * 8192, W2p + (size_t)d * CC * 12288,
            lamT + (size_t)d * CC * NN, stbuf,
            norm_w + (d - 1) * CC, norm_b + (d - 1) * CC);
        bf16* tmp = src; src = dst; dst = tmp;
    }
    // final LN + head, one pass
    ln3_kernel<<<dim3(LL / 256, BB), 256, 0, stream>>>(
        src, norm_w + (DEPTH_ - 1) * CC, norm_b + (DEPTH_ - 1) * CC,
        head_w, head_b, out);
}

// Round 17
// 176.709 us; speedup vs baseline: 2.6884x; 1.0128x over previous
//
#include <hip/hip_runtime.h>
#include <hip/hip_bf16.h>

// S4D regressor, chunked-scan MFMA formulation.
// R17: R16 (green, 179.0 us) + bit-identical latency fills:
//  (a) phase-3 split: ks=0,1 (xf-only) MFMAs issued BEFORE the scan so the
//      matrix pipe crunches during the scan's LDS-latency window; ks=2..5
//      after. o[nf] accumulation order unchanged -> bit-identical.
//  (b) scan batched I/O: 16 pipelined ds_reads -> pure-VALU chain -> 16
//      ds_writes (no interleaved same-address RMW on the chain).
//  (c) p2v+p2w merged into one dispatch.
// B=32, L=4096, C=128, N=64, DEPTH=4, OUT=1.

#define BB     32
#define LL     4096
#define CC     128
#define NN     64
#define DEPTH_ 4
#define EPSV   1e-5f

typedef __attribute__((ext_vector_type(8))) short short8;
typedef __attribute__((ext_vector_type(4))) short short4v;
typedef __attribute__((ext_vector_type(4))) float f32x4;
typedef __hip_bfloat16 bf16;

#define MFMA(a, b, c) __builtin_amdgcn_mfma_f32_16x16x32_bf16(a, b, c, 0, 0, 0)

__device__ __forceinline__ bf16 tobf(float x) { return __float2bfloat16(x); }
__device__ __forceinline__ short bfbits(float x) {
    union { bf16 b; short s; } u; u.b = __float2bfloat16(x); return u.s;
}
__device__ __forceinline__ float frombits(short s) {
    return __uint_as_float(((uint)(ushort)s) << 16);
}

// ---------------------------------------------------------------------------
// P0: per (d,c,n): lam=exp(dt*A), dta=dt*A, cb2=2*C*(lam-1)/A, lamT=lam^64
// ---------------------------------------------------------------------------
__global__ __launch_bounds__(64) void p0_kernel(
    const float* __restrict__ log_dt, const float* __restrict__ A_real,
    const float* __restrict__ A_imag, const float* __restrict__ C_re,
    const float* __restrict__ C_im, float2* __restrict__ lam,
    float2* __restrict__ dta, float2* __restrict__ cb2,
    float2* __restrict__ lamT)
{
    int d = blockIdx.y, c = blockIdx.x, n = threadIdx.x;
    int idx = (d * CC + c) * NN + n;
    float dt  = expf(log_dt[d * CC + c]);
    float Ar  = -expf(A_real[idx]);
    float Ai  = A_imag[idx];
    float dtr = dt * Ar, dti = dt * Ai;
    float e   = expf(dtr);
    float lr  = e * cosf(dti), li = e * sinf(dti);
    float m    = Ar * Ar + Ai * Ai;
    float inv  = 1.0f / m;
    float numr = lr - 1.0f, numi = li;
    float br   = (numr * Ar + numi * Ai) * inv;
    float bi   = (numi * Ar - numr * Ai) * inv;
    float cre  = C_re[idx], cim = C_im[idx];
    lam[idx]  = make_float2(lr, li);
    dta[idx]  = make_float2(dtr, dti);
    cb2[idx]  = make_float2(2.0f * (cre * br - cim * bi),
                            2.0f * (cre * bi + cim * br));
    float eT = expf(64.0f * dtr);
    lamT[idx] = make_float2(eT * cosf(64.0f * dti), eT * sinf(64.0f * dti));
}

// ---------------------------------------------------------------------------
// P1: Kloc[d][c][delta] = Re sum_n cb2_n lam_n^delta   (delta = 0..63)
// ---------------------------------------------------------------------------
__global__ __launch_bounds__(64) void p1_kernel(
    const float2* __restrict__ cb2, const float2* __restrict__ lam,
    float* __restrict__ Kloc)
{
    __shared__ float st[64 * 65];
    int d = blockIdx.y, c = blockIdx.x, n = threadIdx.x;
    float2 p = cb2[(d * CC + c) * NN + n];
    float2 l = lam[(d * CC + c) * NN + n];
    for (int t = 0; t < 64; ++t) {
        st[t * 65 + n] = p.x;
        float nr = p.x * l.x - p.y * l.y;
        p.y = p.x * l.y + p.y * l.x;
        p.x = nr;
    }
    __syncthreads();
    float s = 0.0f;
#pragma unroll 16
    for (int j = 0; j < 64; ++j) s += st[n * 65 + j];
    Kloc[(d * CC + c) * 64 + n] = s;
}

// ---------------------------------------------------------------------------
// P2 (merged): blocks [0, 16384) build Vp; [16384, 40960) build W2p.
// Vp packed [d][c][nf=8][ks=2][lane=64][e=8]; W2p [d][c][nf=4][ks=6][64][8].
// ---------------------------------------------------------------------------
__global__ __launch_bounds__(256) void p2_kernel(
    const float2* __restrict__ dta, const float2* __restrict__ cb2,
    const float* __restrict__ Kloc, const float* __restrict__ Dskip,
    bf16* __restrict__ Vp, bf16* __restrict__ W2p)
{
    int bid = blockIdx.x;
    if (bid < (DEPTH_ * CC * 8192) / 256) {
        int t = bid * 256 + threadIdx.x;
        int e = t & 7, l = (t >> 3) & 63, ks = (t >> 9) & 1;
        int nf = (t >> 10) & 7, c = (t >> 13) & 127, d = t >> 20;
        int q = nf * 16 + (l & 15);
        int k = ks * 32 + (l >> 4) * 8 + e;
        int n = q >> 1;
        float2 a = dta[(d * CC + c) * NN + n];
        float p  = (float)(63 - k);
        float mag = expf(p * a.x);
        float ang = p * a.y;
        float val = (q & 1) ? mag * sinf(ang) : mag * cosf(ang);
        Vp[t] = tobf(val);
    } else {
        int t = (bid - (DEPTH_ * CC * 8192) / 256) * 256 + threadIdx.x;
        int e = t & 7, l = (t >> 3) & 63;
        int r = t >> 9;
        int ks = r % 6; r /= 6;
        int nf = r & 3; r >>= 2;
        int c  = r & 127;
        int d  = r >> 7;
        int i = nf * 16 + (l & 15);
        int k = ks * 32 + (l >> 4) * 8 + e;
        float val;
        if (k < 64) {
            val = (k <= i) ? Kloc[(d * CC + c) * 64 + (i - k)] : 0.0f;
            if (k == i) val += Dskip[d * CC + c] + 1.0f;
        } else {
            int q = k - 64, n = q >> 1;
            float2 a  = dta[(d * CC + c) * NN + n];
            float2 cb = cb2[(d * CC + c) * NN + n];
            float p   = (float)(i + 1);
            float mag = expf(p * a.x);
            float ang = p * a.y;
            float re = mag * cosf(ang), im = mag * sinf(ang);
            float wre = cb.x * re - cb.y * im;
            float wim = cb.x * im + cb.y * re;
            val = (q & 1) ? -wim : wre;
        }
        W2p[t] = tobf(val);
    }
}

// ---------------------------------------------------------------------------
// x [B,L,C] fp32 -> xt [B][C][L] bf16
// ---------------------------------------------------------------------------
__global__ __launch_bounds__(256) void transpose_kernel(
    const float* __restrict__ x, bf16* __restrict__ xt)
{
    __shared__ float t[64][65];
    int ct = blockIdx.x, lt = blockIdx.y, b = blockIdx.z;
    int tx = threadIdx.x & 63, ty = threadIdx.x >> 6;
    const size_t xbase = ((size_t)b * LL + (size_t)lt * 64) * CC + (size_t)ct * 64;
#pragma unroll
    for (int i = 0; i < 16; ++i)
        t[ty + 4 * i][tx] = x[xbase + (size_t)(ty + 4 * i) * CC + tx];
    __syncthreads();
    const size_t obase = ((size_t)b * CC + (size_t)ct * 64) * LL + (size_t)lt * 64;
#pragma unroll
    for (int i = 0; i < 16; ++i)
        xt[obase + (size_t)(ty + 4 * i) * LL + tx] = tobf(t[tx][ty + 4 * i]);
}

// ---------------------------------------------------------------------------
// STATS: per-(b,l) LayerNorm statistics (mean, rstd) from v [B][C][L] bf16.
// ---------------------------------------------------------------------------
__global__ __launch_bounds__(256) void stats_kernel(
    const bf16* __restrict__ v, float2* __restrict__ st)
{
    __shared__ float rs[4][256];
    __shared__ float rq[4][256];
    int b  = blockIdx.y;
    int l0 = blockIdx.x * 256;
    int lt = threadIdx.x & 63;
    int cg = threadIdx.x >> 6;
    const short* vv = (const short*)v;
    float s[4] = {0.f, 0.f, 0.f, 0.f};
    float q[4] = {0.f, 0.f, 0.f, 0.f};
#pragma unroll
    for (int ci = 0; ci < 32; ++ci) {
        int c = cg * 32 + ci;
        short4v r = *(const short4v*)(&vv[((size_t)b * CC + c) * LL + l0 + lt * 4]);
#pragma unroll
        for (int j = 0; j < 4; ++j) {
            float f = frombits(r[j]);
            s[j] += f;
            q[j] = fmaf(f, f, q[j]);
        }
    }
#pragma unroll
    for (int j = 0; j < 4; ++j) {
        rs[cg][lt * 4 + j] = s[j];
        rq[cg][lt * 4 + j] = q[j];
    }
    __syncthreads();
    if (cg == 0) {
#pragma unroll
        for (int j = 0; j < 4; ++j) {
            int li = lt * 4 + j;
            float ts = rs[0][li] + rs[1][li] + rs[2][li] + rs[3][li];
            float tq = rq[0][li] + rq[1][li] + rq[2][li] + rq[3][li];
            float mean = ts * (1.0f / CC);
            float var  = tq * (1.0f / CC) - mean * mean;
            st[(size_t)b * LL + l0 + li] = make_float2(mean, rsqrtf(var + EPSV));
        }
    }
}

// ---------------------------------------------------------------------------
// KS: block = (c, 8 b's), 512 threads. Weights (40 KB) staged in LDS once.
// Per group: normalize -> phase1 -> [phase3a: ks=0,1 MFMAs] -> prefetch ->
// batched scan -> [phase3b: ks=2..5] -> store. One barrier total.
// ---------------------------------------------------------------------------
__global__ __launch_bounds__(512) void ks_kernel(
    const bf16* __restrict__ u, bf16* __restrict__ v,
    const bf16* __restrict__ Vp, const bf16* __restrict__ W2p,
    const float2* __restrict__ lamT, const float2* __restrict__ st,
    const float* __restrict__ nw, const float* __restrict__ nb)
{
    const int c  = blockIdx.x;             // channel owned by this block
    const int w  = threadIdx.x >> 6;       // wave 0..7 -> b = bg*8+w
    const int l  = threadIdx.x & 63;       // lane: MFMA lane AND mode index n
    const int b  = blockIdx.y * 8 + w;
    const int bc = b * CC + c;
    const bf16* xrow = u + (size_t)bc * LL;
    bf16*       vrow = v + (size_t)bc * LL;

    __shared__ short Wl[8192 + 12288];     // Vp(16KB) + W2p(24KB) = 40 KB
    __shared__ short Sp[8][16 * 136];      // per-wave 4.35 KB scan slice

    // ---- stage weights: 2560 x uint4 across 512 threads, one barrier ----
    {
        uint4*       dst  = (uint4*)Wl;
        const uint4* srcV = (const uint4*)(Vp  + (size_t)c * 8192);
        const uint4* srcW = (const uint4*)(W2p + (size_t)c * 12288);
        int tid = threadIdx.x;
#pragma unroll
        for (int i = 0; i < 2; ++i)
            dst[tid + 512 * i] = srcV[tid + 512 * i];
#pragma unroll
        for (int i = 0; i < 3; ++i)
            dst[1024 + tid + 512 * i] = srcW[tid + 512 * i];
    }
    __syncthreads();                       // the ONLY barrier

    short* S = Sp[w];
    const short* W2l = Wl + 8192;
    const int mloc = l & 15;               // chunk-within-group (MFMA B-col)
    const int koff = (l >> 4) * 8;
    float2 lt = lamT[c * NN + l];
    float sr = 0.f, si = 0.f;              // running state, f32 entire L

    const float2* stb = st ? (st + (size_t)b * LL) : nullptr;
    float wc = 0.f, bcf = 0.f;
    if (st) { wc = nw[c]; bcf = nb[c]; }

    // ---- prefetch group 0's raw x fragments ----
    short8 xf0 = *(const short8*)(xrow + mloc * 64 + koff);
    short8 xf1 = *(const short8*)(xrow + mloc * 64 + koff + 32);

#pragma unroll 1
    for (int g = 0; g < 4; ++g) {
        const int lbase = (g * 16 + mloc) * 64 + koff;

        // ---- normalize current fragments (float4 stat loads) ----
        if (stb) {
            const float4* sq0 = (const float4*)(stb + lbase);
            const float4* sq1 = (const float4*)(stb + lbase + 32);
#pragma unroll
            for (int i = 0; i < 4; ++i) {
                float4 p0 = sq0[i], p1 = sq1[i];
                float a00 = p0.y * wc, a01 = p0.w * wc;
                float a10 = p1.y * wc, a11 = p1.w * wc;
                xf0[2 * i]     = bfbits(fmaf(frombits(xf0[2 * i]),     a00, fmaf(-p0.x, a00, bcf)));
                xf0[2 * i + 1] = bfbits(fmaf(frombits(xf0[2 * i + 1]), a01, fmaf(-p0.z, a01, bcf)));
                xf1[2 * i]     = bfbits(fmaf(frombits(xf1[2 * i]),     a10, fmaf(-p1.x, a10, bcf)));
                xf1[2 * i + 1] = bfbits(fmaf(frombits(xf1[2 * i + 1]), a11, fmaf(-p1.z, a11, bcf)));
            }
        }

        // ---- phase 1 (two 4-nf halves to cap acc pressure) ----
#pragma unroll
        for (int h = 0; h < 2; ++h) {
            f32x4 acc[4];
#pragma unroll
            for (int j = 0; j < 4; ++j) acc[j] = (f32x4){0.f, 0.f, 0.f, 0.f};
#pragma unroll
            for (int j = 0; j < 4; ++j) {
                int nf = h * 4 + j;
                short8 vf0 = *(const short8*)(&Wl[((nf * 2 + 0) * 64 + l) * 8]);
                short8 vf1 = *(const short8*)(&Wl[((nf * 2 + 1) * 64 + l) * 8]);
                acc[j] = MFMA(vf0, xf0, acc[j]);
                acc[j] = MFMA(vf1, xf1, acc[j]);
            }
#pragma unroll
            for (int j = 0; j < 4; ++j) {
                int nf = h * 4 + j;
                short4v t;
                t[0] = bfbits(acc[j][0]); t[1] = bfbits(acc[j][1]);
                t[2] = bfbits(acc[j][2]); t[3] = bfbits(acc[j][3]);
                *(short4v*)(&S[mloc * 136 + nf * 16 + (l >> 4) * 4]) = t;
            }
        }
        asm volatile("" ::: "memory");     // same-wave DS pipe is in-order

        // ---- phase 3a: ks=0,1 (xf-only) — overlaps the scan's stalls ----
        f32x4 o[4];
#pragma unroll
        for (int nf = 0; nf < 4; ++nf) o[nf] = (f32x4){0.f, 0.f, 0.f, 0.f};
#pragma unroll
        for (int nf = 0; nf < 4; ++nf) {
            short8 wf0 = *(const short8*)(&W2l[((nf * 6 + 0) * 64 + l) * 8]);
            o[nf] = MFMA(wf0, xf0, o[nf]);
            short8 wf1 = *(const short8*)(&W2l[((nf * 6 + 1) * 64 + l) * 8]);
            o[nf] = MFMA(wf1, xf1, o[nf]);
        }

        // ---- prefetch next group's raw x fragments ----
        const int gn = (g < 3) ? g + 1 : 3;
        const int lbn = (gn * 16 + mloc) * 64 + koff;
        short8 nxf0 = *(const short8*)(xrow + lbn);
        short8 nxf1 = *(const short8*)(xrow + lbn + 32);

        // ---- scan: batched reads -> VALU chain -> batched writes ----
        uint pk[16];
#pragma unroll
        for (int k = 0; k < 16; ++k)
            pk[k] = *(const uint*)(&S[k * 136 + 2 * l]);
#pragma unroll
        for (int k = 0; k < 16; ++k) {
            uint p = pk[k];
            union { short2 s2; uint uu; } o2;
            o2.s2.x = bfbits(sr); o2.s2.y = bfbits(si);
            pk[k] = o2.uu;                 // Sprev for chunk k
            float pr = __uint_as_float(p << 16);
            float pi = __uint_as_float(p & 0xffff0000u);
            float nr = fmaf(lt.x, sr, fmaf(-lt.y, si, pr));
            si = fmaf(lt.x, si, fmaf(lt.y, sr, pi));
            sr = nr;
        }
#pragma unroll
        for (int k = 0; k < 16; ++k)
            *(uint*)(&S[k * 136 + 2 * l]) = pk[k];
        asm volatile("" ::: "memory");

        // ---- phase 3b: ks=2..5 from Sprev ----
#pragma unroll
        for (int ks = 2; ks < 6; ++ks) {
            short8 xf = *(const short8*)(&S[mloc * 136 + (ks - 2) * 32 + koff]);
#pragma unroll
            for (int nf = 0; nf < 4; ++nf) {
                short8 wf = *(const short8*)(&W2l[((nf * 6 + ks) * 64 + l) * 8]);
                o[nf] = MFMA(wf, xf, o[nf]);
            }
        }
#pragma unroll
        for (int nf = 0; nf < 4; ++nf) {
            short4v t;
            t[0] = bfbits(o[nf][0]); t[1] = bfbits(o[nf][1]);
            t[2] = bfbits(o[nf][2]); t[3] = bfbits(o[nf][3]);
            *(short4v*)(vrow + (g * 16 + mloc) * 64 + nf * 16 + (l >> 4) * 4) = t;
        }

        xf0 = nxf0;                        // rotate prefetched fragments
        xf1 = nxf1;
    }
}

// ---------------------------------------------------------------------------
// LN3: final LayerNorm + head in ONE pass over v.
//   out[b,l] = rstd*( sum_c v*wh_c - mu*S1 ) + S2
// ---------------------------------------------------------------------------
__global__ __launch_bounds__(256) void ln3_kernel(
    const bf16* __restrict__ v,
    const float* __restrict__ w, const float* __restrict__ bta,
    const float* __restrict__ headw, const float* __restrict__ headb,
    float* __restrict__ fout)
{
    __shared__ float rs[4][256];
    __shared__ float rq[4][256];
    __shared__ float rh[4][256];
    __shared__ float r1s[4];
    __shared__ float r2s[4];
    int b  = blockIdx.y;
    int l0 = blockIdx.x * 256;
    int lt = threadIdx.x & 63;
    int cg = threadIdx.x >> 6;
    const short* vv = (const short*)v;
    float s[4] = {0.f, 0.f, 0.f, 0.f};
    float q[4] = {0.f, 0.f, 0.f, 0.f};
    float h[4] = {0.f, 0.f, 0.f, 0.f};
    float ps1 = 0.f, ps2 = 0.f;
#pragma unroll
    for (int ci = 0; ci < 32; ++ci) {
        int c = cg * 32 + ci;
        float hwc = headw[c];
        float whc = w[c] * hwc;
        ps1 += whc;
        ps2 = fmaf(bta[c], hwc, ps2);
        short4v r = *(const short4v*)(&vv[((size_t)b * CC + c) * LL + l0 + lt * 4]);
#pragma unroll
        for (int j = 0; j < 4; ++j) {
            float f = frombits(r[j]);
            s[j] += f;
            q[j] = fmaf(f, f, q[j]);
            h[j] = fmaf(f, whc, h[j]);
        }
    }
#pragma unroll
    for (int j = 0; j < 4; ++j) {
        rs[cg][lt * 4 + j] = s[j];
        rq[cg][lt * 4 + j] = q[j];
        rh[cg][lt * 4 + j] = h[j];
    }
    if (lt == 0) { r1s[cg] = ps1; r2s[cg] = ps2; }
    __syncthreads();
    if (cg == 0) {
        float S1 = r1s[0] + r1s[1] + r1s[2] + r1s[3];
        float S2 = r2s[0] + r2s[1] + r2s[2] + r2s[3] + headb[0];
#pragma unroll
        for (int j = 0; j < 4; ++j) {
            int li = lt * 4 + j;
            float ts = rs[0][li] + rs[1][li] + rs[2][li] + rs[3][li];
            float tq = rq[0][li] + rq[1][li] + rq[2][li] + rq[3][li];
            float th = rh[0][li] + rh[1][li] + rh[2][li] + rh[3][li];
            float mean = ts * (1.0f / CC);
            float var  = tq * (1.0f / CC) - mean * mean;
            float rstd = rsqrtf(var + EPSV);
            fout[(size_t)b * LL + l0 + li] = rstd * (th - mean * S1) + S2;
        }
    }
}

// ---------------------------------------------------------------------------
extern "C" void kernel_launch(void* const* d_in, const int* in_sizes, int n_in,
                              void* d_out, int out_size, void* d_ws, size_t ws_size,
                              hipStream_t stream)
{
    const float* x      = (const float*)d_in[0];
    const float* log_dt = (const float*)d_in[1];
    const float* A_real = (const float*)d_in[2];
    const float* A_imag = (const float*)d_in[3];
    const float* C_re   = (const float*)d_in[4];
    const float* C_im   = (const float*)d_in[5];
    const float* Dskip  = (const float*)d_in[6];
    const float* norm_w = (const float*)d_in[7];
    const float* norm_b = (const float*)d_in[8];
    const float* head_w = (const float*)d_in[9];
    const float* head_b = (const float*)d_in[10];
    float* out = (float*)d_out;

    const size_t DCN = (size_t)DEPTH_ * CC * NN;
    const size_t BCL = (size_t)BB * CC * LL;

    float2* lam  = (float2*)d_ws;
    float2* dta  = lam + DCN;
    float2* cb2  = dta + DCN;
    float2* lamT = cb2 + DCN;
    float*  Kloc = (float*)(lamT + DCN);
    bf16*   A    = (bf16*)(Kloc + (size_t)DEPTH_ * CC * 64);
    bf16*   Bb   = A + BCL;
    bf16*   Vp   = Bb + BCL;
    bf16*   W2p  = Vp + (size_t)DEPTH_ * CC * 8192;
    float2* stbuf = (float2*)(W2p + (size_t)DEPTH_ * CC * 12288);  // B*L float2

    p0_kernel<<<dim3(CC, DEPTH_), 64, 0, stream>>>(
        log_dt, A_real, A_imag, C_re, C_im, lam, dta, cb2, lamT);
    p1_kernel<<<dim3(CC, DEPTH_), 64, 0, stream>>>(cb2, lam, Kloc);
    p2_kernel<<<(DEPTH_ * CC * 8192) / 256 + (DEPTH_ * CC * 12288) / 256,
                256, 0, stream>>>(dta, cb2, Kloc, Dskip, Vp, W2p);
    transpose_kernel<<<dim3(CC / 64, LL / 64, BB), 256, 0, stream>>>(x, A);

    // d=0: A -> Bb (no input norm)
    ks_kernel<<<dim3(CC, BB / 8), 512, 0, stream>>>(
        A, Bb, Vp, W2p, lamT, nullptr, nullptr, nullptr);
    // middle layers: stats then normalized ks
    bf16* src = Bb;
    bf16* dst = A;
    for (int d = 1; d < DEPTH_; ++d) {
        stats_kernel<<<dim3(LL / 256, BB), 256, 0, stream>>>(src, stbuf);
        ks_kernel<<<dim3(CC, BB / 8), 512, 0, stream>>>(
            src, dst, Vp + (size_t)d * CC * 8192, W2p + (size_t)d * CC * 12288,
            lamT + (size_t)d * CC * NN, stbuf,
            norm_w + (d - 1) * CC, norm_b + (d - 1) * CC);
        bf16* tmp = src; src = dst; dst = tmp;
    }
    // final LN + head, one pass
    ln3_kernel<<<dim3(LL / 256, BB), 256, 0, stream>>>(
        src, norm_w + (DEPTH_ - 1) * CC, norm_b + (DEPTH_ - 1) * CC,
        head_w, head_b, out);
}